// Round 9
// baseline (117.010 us; speedup 1.0000x reference)
//
#include <hip/hip_runtime.h>
#include <hip/hip_fp16.h>

// GCN encoder, N=50000, E=800000, 128 -> 96 (relu) -> sum-pooled 64+64.
// Sum-pooled layer 2: out = (sum_u c[u]*h[u]) @ W + N*b,
//   c[u] = dinv[u]*(dinv[u] + rsum[u]),  rsum[u] = sum_{e: src=u} dinv[dst_e].
// Layer 1 with g[u] = (xW1)[u]*dinv[u]  (fp8 e4m3, x16 scale):
//   h[d] = relu( (dinv[d]/16)*(sum_{e->d} g_s[src] + g_s[d]) + b1 )
// 6 kernels: count -> scanoffs (lookback scan, all-resident) -> place
// (slice-major: col writes XCD-owned) -> gemm(+cfac) -> agg -> vred+out.

#define NCHUNK 32
#define LOG_NCHUNK 5
#define NSLICE 8
#define SLICE_MAX 6272   // LDS hist capacity; N <= 8*6272
#define SORT_T 1024      // threads for count/place
#define ZN 200           // zero-state ints: zagg[196] + cnt

typedef float v2f __attribute__((ext_vector_type(2)));

__device__ inline void fma4(float4& c, float a, const float4& b) {
    c.x = fmaf(a, b.x, c.x); c.y = fmaf(a, b.y, c.y);
    c.z = fmaf(a, b.z, c.z); c.w = fmaf(a, b.w, c.w);
}

// pack 4 floats -> 4 x fp8 e4m3 in one uint
__device__ inline unsigned pk_fp8(float a, float b, float c, float d) {
    int p = __builtin_amdgcn_cvt_pk_fp8_f32(a, b, 0, false);
    p = __builtin_amdgcn_cvt_pk_fp8_f32(c, d, p, true);
    return (unsigned)p;
}

// ---- K1: per-(chunk,slice) dst histogram via LDS; block 0 zeroes scan state ----
// c = bid & 31 (chunk-major): a chunk's 8 slice-blocks share one XCD's L2.
__launch_bounds__(SORT_T)
__global__ void k_count(const int* __restrict__ dst, int* __restrict__ partial,
                        int* __restrict__ zst, int N, int E, int chunkE, int sliceN) {
    if (blockIdx.x == 0) {
        for (int j = threadIdx.x; j < ZN; j += SORT_T) zst[j] = 0;
    }
    int c = blockIdx.x & (NCHUNK - 1), s = blockIdx.x >> LOG_NCHUNK;
    int nbase = s * sliceN;
    __shared__ int hist[SLICE_MAX];
    for (int j = threadIdx.x; j < sliceN; j += SORT_T) hist[j] = 0;
    __syncthreads();
    int e0 = c * chunkE, e1 = min(e0 + chunkE, E);
    int ne = e1 - e0;
    const int4* d4 = (const int4*)(dst + e0);
    int n4 = ne >> 2;
    for (int i = threadIdx.x; i < n4; i += SORT_T) {
        int4 d = d4[i];
        unsigned q;
        q = (unsigned)(d.x - nbase); if (q < (unsigned)sliceN) atomicAdd(&hist[q], 1);
        q = (unsigned)(d.y - nbase); if (q < (unsigned)sliceN) atomicAdd(&hist[q], 1);
        q = (unsigned)(d.z - nbase); if (q < (unsigned)sliceN) atomicAdd(&hist[q], 1);
        q = (unsigned)(d.w - nbase); if (q < (unsigned)sliceN) atomicAdd(&hist[q], 1);
    }
    if (threadIdx.x < (ne & 3)) {
        int d = dst[e0 + (n4 << 2) + threadIdx.x];
        unsigned q = (unsigned)(d - nbase);
        if (q < (unsigned)sliceN) atomicAdd(&hist[q], 1);
    }
    __syncthreads();
    for (int j = threadIdx.x; j < sliceN; j += SORT_T) {
        int n = nbase + j;
        if (n < N) partial[(size_t)c * N + n] = hist[j];
    }
}

// ---- K2: deg-sum -> dinv; all-resident lookback scan -> rowptr;
//      partial counts -> absolute offsets. Replaces degdinv+bscan+offs. ----
__launch_bounds__(256)
__global__ void k_scanoffs(int* __restrict__ partial, float* __restrict__ dinv,
                           int* __restrict__ zagg, int* __restrict__ rowptr,
                           int N, int E) {
    int tid = threadIdx.x;
    int b = blockIdx.x;
    int n = b * 256 + tid;
    int deg = 0;
    if (n < N) {
        #pragma unroll
        for (int c = 0; c < NCHUNK; ++c) deg += partial[(size_t)c * N + n];
        dinv[n] = rsqrtf((float)(deg + 1));
    }
    __shared__ int sh[256];
    sh[tid] = deg;
    __syncthreads();
    for (int off = 1; off < 256; off <<= 1) {
        int t = (tid >= off) ? sh[tid - off] : 0;
        __syncthreads();
        sh[tid] += t;
        __syncthreads();
    }
    int incl = sh[tid];
    int btot = sh[255];
    if (tid == 0) atomicExch(&zagg[b], btot + 1);   // publish (sentinel 0 = not ready)
    // lookback: thread t spins on predecessor t (all blocks co-resident, no deadlock)
    __shared__ int s_off;
    if (tid == 0) s_off = 0;
    __syncthreads();
    if (tid < b) {
        int v;
        while ((v = atomicAdd(&zagg[tid], 0)) == 0) __builtin_amdgcn_s_sleep(1);
        atomicAdd(&s_off, v - 1);
    }
    __syncthreads();
    int run = s_off + incl - deg;   // global exclusive prefix
    if (n < N) {
        rowptr[n] = run;
        #pragma unroll
        for (int c = 0; c < NCHUNK; ++c) {
            size_t ix = (size_t)c * N + n;
            int t = partial[ix];
            partial[ix] = run;
            run += t;
        }
    }
    if (b == 0 && tid == 0) rowptr[N] = E;
}

// ---- K3: place edges into col via LDS cursors; rsum partials into offs (dead).
// Slice-major: s = bid&7 -> all writers of a dst-slice share one XCD (col line
// ownership, no cross-XCD 64B ping-pong); chunk reads come from L3. ----
__launch_bounds__(SORT_T)
__global__ void k_place(const int* __restrict__ src, const int* __restrict__ dst,
                        const float* __restrict__ dinv, int* __restrict__ offs,
                        int* __restrict__ col, int N, int E, int chunkE, int sliceN) {
    int s = blockIdx.x & (NSLICE - 1), c = blockIdx.x >> 3;
    int nbase = s * sliceN;
    __shared__ int cur[SLICE_MAX];
    __shared__ float rs[SLICE_MAX];
    for (int j = threadIdx.x; j < sliceN; j += SORT_T) {
        int n = nbase + j;
        cur[j] = (n < N) ? offs[(size_t)c * N + n] : 0;
        rs[j] = 0.f;
    }
    __syncthreads();
    int e0 = c * chunkE, e1 = min(e0 + chunkE, E);
    int ne = e1 - e0;
    const int4* s4 = (const int4*)(src + e0);
    const int4* d4 = (const int4*)(dst + e0);
    int n4 = ne >> 2;
    for (int i = threadIdx.x; i < n4; i += SORT_T) {
        int4 sv = s4[i];
        int4 dv = d4[i];
        unsigned qd, qs;
        qd = (unsigned)(dv.x - nbase);
        if (qd < (unsigned)sliceN) { int p = atomicAdd(&cur[qd], 1); col[p] = sv.x; }
        qs = (unsigned)(sv.x - nbase);
        if (qs < (unsigned)sliceN) atomicAdd(&rs[qs], dinv[dv.x]);
        qd = (unsigned)(dv.y - nbase);
        if (qd < (unsigned)sliceN) { int p = atomicAdd(&cur[qd], 1); col[p] = sv.y; }
        qs = (unsigned)(sv.y - nbase);
        if (qs < (unsigned)sliceN) atomicAdd(&rs[qs], dinv[dv.y]);
        qd = (unsigned)(dv.z - nbase);
        if (qd < (unsigned)sliceN) { int p = atomicAdd(&cur[qd], 1); col[p] = sv.z; }
        qs = (unsigned)(sv.z - nbase);
        if (qs < (unsigned)sliceN) atomicAdd(&rs[qs], dinv[dv.z]);
        qd = (unsigned)(dv.w - nbase);
        if (qd < (unsigned)sliceN) { int p = atomicAdd(&cur[qd], 1); col[p] = sv.w; }
        qs = (unsigned)(sv.w - nbase);
        if (qs < (unsigned)sliceN) atomicAdd(&rs[qs], dinv[dv.w]);
    }
    if (threadIdx.x < (ne & 3)) {
        int e = e0 + (n4 << 2) + threadIdx.x;
        int sv = src[e], dv = dst[e];
        unsigned qd = (unsigned)(dv - nbase);
        if (qd < (unsigned)sliceN) { int p = atomicAdd(&cur[qd], 1); col[p] = sv; }
        unsigned qs = (unsigned)(sv - nbase);
        if (qs < (unsigned)sliceN) atomicAdd(&rs[qs], dinv[dv]);
    }
    __syncthreads();
    float* prs = (float*)offs;   // offs[c][this slice] dead after load -> reuse
    for (int j = threadIdx.x; j < sliceN; j += SORT_T) {
        int n = nbase + j;
        if (n < N) prs[(size_t)c * N + n] = rs[j];
    }
}

// ---- K4: g = fp8(16*(x @ W1)*dinv[row]); fused cfac = dinv*(dinv+rsum) ----
__launch_bounds__(256)
__global__ void k_gemm(const float* __restrict__ x, const float* __restrict__ W1,
                       const float* __restrict__ dinv, const float* __restrict__ prs,
                       float* __restrict__ cfac, unsigned* __restrict__ g, int n) {
    __shared__ float Ws[128 * 96];
    int tid = threadIdx.x;
    {
        const float4* wsrc = (const float4*)W1;
        float4* wdst = (float4*)Ws;
        #pragma unroll
        for (int i = 0; i < 12; ++i) wdst[tid + 256 * i] = wsrc[tid + 256 * i];
    }
    // fused rsum->cfac for this block's 128 rows (overlaps staging)
    {
        int r = blockIdx.x * 128 + tid;
        if (tid < 128 && r < n) {
            float s = 0.f;
            #pragma unroll
            for (int c = 0; c < NCHUNK; ++c) s += prs[(size_t)c * n + r];
            float dv = dinv[r];
            cfac[r] = dv * (dv + s);
        }
    }
    __syncthreads();

    int tx = tid & 7;          // 8 col groups of 12
    int ty = tid >> 3;         // 32 row quads
    int rbase = blockIdx.x * 128 + ty * 4;
    const float4* xp[4];
    bool vr[4];
    #pragma unroll
    for (int i = 0; i < 4; ++i) {
        int r = rbase + i;
        vr[i] = r < n;
        xp[i] = (const float4*)(x + (size_t)(vr[i] ? r : 0) * 128);
    }

    float4 acc[4][3];
    #pragma unroll
    for (int i = 0; i < 4; ++i)
        #pragma unroll
        for (int j = 0; j < 3; ++j) acc[i][j] = make_float4(0.f, 0.f, 0.f, 0.f);

    #pragma unroll 2
    for (int k4 = 0; k4 < 32; ++k4) {
        float4 a0 = xp[0][k4];
        float4 a1 = xp[1][k4];
        float4 a2 = xp[2][k4];
        float4 a3 = xp[3][k4];
        #pragma unroll
        for (int kk = 0; kk < 4; ++kk) {
            const float* wrow = &Ws[(k4 * 4 + kk) * 96 + tx * 12];
            float4 b0 = *(const float4*)(wrow);
            float4 b1 = *(const float4*)(wrow + 4);
            float4 b2 = *(const float4*)(wrow + 8);
            float av0 = (kk == 0) ? a0.x : (kk == 1) ? a0.y : (kk == 2) ? a0.z : a0.w;
            float av1 = (kk == 0) ? a1.x : (kk == 1) ? a1.y : (kk == 2) ? a1.z : a1.w;
            float av2 = (kk == 0) ? a2.x : (kk == 1) ? a2.y : (kk == 2) ? a2.z : a2.w;
            float av3 = (kk == 0) ? a3.x : (kk == 1) ? a3.y : (kk == 2) ? a3.z : a3.w;
            fma4(acc[0][0], av0, b0); fma4(acc[0][1], av0, b1); fma4(acc[0][2], av0, b2);
            fma4(acc[1][0], av1, b0); fma4(acc[1][1], av1, b1); fma4(acc[1][2], av1, b2);
            fma4(acc[2][0], av2, b0); fma4(acc[2][1], av2, b1); fma4(acc[2][2], av2, b2);
            fma4(acc[3][0], av3, b0); fma4(acc[3][1], av3, b1); fma4(acc[3][2], av3, b2);
        }
    }

    #pragma unroll
    for (int i = 0; i < 4; ++i) {
        if (!vr[i]) continue;
        int r = rbase + i;
        float dv = dinv[r] * 16.f;      // x16 scale for fp8 dynamic range
        unsigned* o = g + (size_t)r * 24 + tx * 3;
        float4 t;
        t = acc[i][0]; o[0] = pk_fp8(t.x * dv, t.y * dv, t.z * dv, t.w * dv);
        t = acc[i][1]; o[1] = pk_fp8(t.x * dv, t.y * dv, t.z * dv, t.w * dv);
        t = acc[i][2]; o[2] = pk_fp8(t.x * dv, t.y * dv, t.z * dv, t.w * dv);
    }
}

// ---- K5: per-node fp8 gather + fused bias/relu/cfac + block partial of v ----
#define AGG_NODES 16
#define AGG_T (AGG_NODES * 24)
__launch_bounds__(AGG_T)
__global__ void k_agg(const unsigned* __restrict__ g1, const int* __restrict__ col,
                      const int* __restrict__ rowptr, const float* __restrict__ dinv,
                      const float* __restrict__ cfac, const float* __restrict__ b1,
                      float* __restrict__ v_part, int n) {
    int tid = threadIdx.x;
    int nl = tid / 24;
    int ch = tid % 24;        // uint chunk of the 24-uint row (4 fp8 each)
    int d = blockIdx.x * AGG_NODES + nl;

    __shared__ float4 sh[AGG_NODES][24];

    float4 contrib = make_float4(0.f, 0.f, 0.f, 0.f);
    if (d < n) {
        float dds = dinv[d] * 0.0625f;   // undo x16 storage scale
        int e0 = rowptr[d], e1 = rowptr[d + 1];
        float4 aA = make_float4(0.f, 0.f, 0.f, 0.f);
        float4 aB = make_float4(0.f, 0.f, 0.f, 0.f);
        int e = e0;
        for (; e + 4 <= e1; e += 4) {
            int s0 = col[e], s1 = col[e + 1], s2 = col[e + 2], s3 = col[e + 3];
            unsigned u0 = g1[(size_t)s0 * 24 + ch];
            unsigned u1 = g1[(size_t)s1 * 24 + ch];
            unsigned u2 = g1[(size_t)s2 * 24 + ch];
            unsigned u3 = g1[(size_t)s3 * 24 + ch];
            v2f f;
            f = __builtin_amdgcn_cvt_pk_f32_fp8(u0, false); aA.x += f.x; aA.y += f.y;
            f = __builtin_amdgcn_cvt_pk_f32_fp8(u0, true);  aA.z += f.x; aA.w += f.y;
            f = __builtin_amdgcn_cvt_pk_f32_fp8(u1, false); aB.x += f.x; aB.y += f.y;
            f = __builtin_amdgcn_cvt_pk_f32_fp8(u1, true);  aB.z += f.x; aB.w += f.y;
            f = __builtin_amdgcn_cvt_pk_f32_fp8(u2, false); aA.x += f.x; aA.y += f.y;
            f = __builtin_amdgcn_cvt_pk_f32_fp8(u2, true);  aA.z += f.x; aA.w += f.y;
            f = __builtin_amdgcn_cvt_pk_f32_fp8(u3, false); aB.x += f.x; aB.y += f.y;
            f = __builtin_amdgcn_cvt_pk_f32_fp8(u3, true);  aB.z += f.x; aB.w += f.y;
        }
        for (; e < e1; ++e) {
            unsigned u = g1[(size_t)col[e] * 24 + ch];
            v2f f;
            f = __builtin_amdgcn_cvt_pk_f32_fp8(u, false); aA.x += f.x; aA.y += f.y;
            f = __builtin_amdgcn_cvt_pk_f32_fp8(u, true);  aA.z += f.x; aA.w += f.y;
        }
        {   // analytic self-loop: g[d] joins the same sum
            unsigned u = g1[(size_t)d * 24 + ch];
            v2f f;
            f = __builtin_amdgcn_cvt_pk_f32_fp8(u, false); aA.x += f.x; aA.y += f.y;
            f = __builtin_amdgcn_cvt_pk_f32_fp8(u, true);  aA.z += f.x; aA.w += f.y;
        }
        float4 b1c = ((const float4*)b1)[ch];
        float cd = cfac[d];
        float hx = fmaxf(fmaf(dds, aA.x + aB.x, b1c.x), 0.f);
        float hy = fmaxf(fmaf(dds, aA.y + aB.y, b1c.y), 0.f);
        float hz = fmaxf(fmaf(dds, aA.z + aB.z, b1c.z), 0.f);
        float hw = fmaxf(fmaf(dds, aA.w + aB.w, b1c.w), 0.f);
        contrib = make_float4(cd * hx, cd * hy, cd * hz, cd * hw);
    }
    sh[nl][ch] = contrib;
    __syncthreads();
    #pragma unroll
    for (int off = 8; off >= 1; off >>= 1) {
        if (nl < off) {
            float4 a = sh[nl][ch];
            float4 b = sh[nl + off][ch];
            a.x += b.x; a.y += b.y; a.z += b.z; a.w += b.w;
            sh[nl][ch] = a;
        }
        __syncthreads();
    }
    if (tid < 24) {
        ((float4*)(v_part + (size_t)blockIdx.x * 96))[tid] = sh[0][tid];
    }
}

// ---- K6: v_part column-reduce; last block computes mu/logvar matvecs ----
__launch_bounds__(256)
__global__ void k_vredout(const float* __restrict__ vp, float* __restrict__ v,
                          int* __restrict__ cnt, int nb,
                          const float* __restrict__ Wmu, const float* __restrict__ bmu,
                          const float* __restrict__ Wlv, const float* __restrict__ blv,
                          float* __restrict__ out, float nN) {
    int j = blockIdx.x;   // 96 blocks
    int tid = threadIdx.x;
    float s = 0.f;
    for (int i = tid; i < nb; i += 256) s += vp[(size_t)i * 96 + j];
    __shared__ float sh[256];
    sh[tid] = s;
    __syncthreads();
    for (int off = 128; off; off >>= 1) {
        if (tid < off) sh[tid] += sh[tid + off];
        __syncthreads();
    }
    __shared__ int s_last;
    if (tid == 0) {
        atomicExch((unsigned*)&v[j], __float_as_uint(sh[0]));  // device-scope publish
        __threadfence();
        s_last = (atomicAdd(cnt, 1) == 95);
    }
    __syncthreads();
    if (!s_last) return;
    // last block: device-coherent read of all 96 v values, then matvecs
    __shared__ float vv[96];
    if (tid < 96) vv[tid] = __uint_as_float(atomicAdd((unsigned*)&v[tid], 0u));
    __syncthreads();
    if (tid < 128) {
        const float* W = (tid < 64) ? Wmu : Wlv;
        const float* b = (tid < 64) ? bmu : blv;
        int jj = tid & 63;
        float acc = 0.f;
        #pragma unroll
        for (int k = 0; k < 96; ++k) acc = fmaf(vv[k], W[k * 64 + jj], acc);
        out[tid] = acc + nN * b[jj];
    }
}

extern "C" void kernel_launch(void* const* d_in, const int* in_sizes, int n_in,
                              void* d_out, int out_size, void* d_ws, size_t ws_size,
                              hipStream_t stream) {
    const float* x   = (const float*)d_in[0];
    const int*   ei  = (const int*)d_in[1];
    const float* W1  = (const float*)d_in[2];
    const float* b1  = (const float*)d_in[3];
    const float* Wmu = (const float*)d_in[4];
    const float* bmu = (const float*)d_in[5];
    const float* Wlv = (const float*)d_in[6];
    const float* blv = (const float*)d_in[7];
    float* out = (float*)d_out;

    const int N = in_sizes[0] / 128;   // 50000
    const int E = in_sizes[1] / 2;     // 800000
    const int* src = ei;
    const int* dst = ei + E;

    const int chunkE = (((E + NCHUNK - 1) / NCHUNK) + 3) & ~3;   // 25000
    const int sliceN = (N + NSLICE - 1) / NSLICE;                // 6250
    const int gN = (N + 255) / 256;                              // 196

    size_t off = 0;
    auto alloc = [&](size_t bytes) -> char* {
        off = (off + 255) & ~(size_t)255;
        char* p = (char*)d_ws + off;
        off += bytes;
        return p;
    };
    int*      partial = (int*)alloc((size_t)NCHUNK * N * 4);  // counts->offs->rsum partials
    int*      rowptr  = (int*)alloc((size_t)(N + 1) * 4);
    int*      col     = (int*)alloc((size_t)E * 4);
    float*    dinv    = (float*)alloc((size_t)N * 4);
    float*    cfac    = (float*)alloc((size_t)N * 4);
    int*      zst     = (int*)alloc((size_t)ZN * 4);          // zagg[196] + cnt
    unsigned* g       = (unsigned*)alloc((size_t)N * 96);     // fp8 e4m3, 24 uints/row
    const int nAggBlocks = (N + AGG_NODES - 1) / AGG_NODES;   // 3125
    float*    v_part  = (float*)alloc((size_t)nAggBlocks * 96 * 4);
    float*    v       = (float*)alloc(96 * 4);

    int* zagg = zst;          // [196]
    int* cnt  = zst + 196;    // [1]

    k_count<<<NCHUNK * NSLICE, SORT_T, 0, stream>>>(dst, partial, zst, N, E, chunkE, sliceN);
    k_scanoffs<<<gN, 256, 0, stream>>>(partial, dinv, zagg, rowptr, N, E);
    k_place<<<NCHUNK * NSLICE, SORT_T, 0, stream>>>(src, dst, dinv, partial, col, N, E, chunkE, sliceN);
    k_gemm<<<(N + 127) / 128, 256, 0, stream>>>(x, W1, dinv, (const float*)partial, cfac, g, N);
    k_agg<<<nAggBlocks, AGG_T, 0, stream>>>(g, col, rowptr, dinv, cfac, b1, v_part, N);
    k_vredout<<<96, 256, 0, stream>>>(v_part, v, cnt, nAggBlocks, Wmu, bmu, Wlv, blv, out, (float)N);
}

// Round 10
// 115.791 us; speedup vs baseline: 1.0105x; 1.0105x over previous
//
#include <hip/hip_runtime.h>
#include <hip/hip_fp16.h>

// GCN encoder, N=50000, E=800000, 128 -> 96 (relu) -> sum-pooled 64+64.
// Sum-pooled layer 2: out = (sum_u c[u]*h[u]) @ W + N*b,
//   c[u] = dinv[u]*(dinv[u] + rsum[u]),  rsum[u] = sum_{e: src=u} dinv[dst_e].
// Layer 1 with g[u] = (xW1)[u]*dinv[u]  (fp8 e4m3, x16 scale):
//   h[d] = relu( (dinv[d]/16)*(sum_{e->d} g_s[src] + g_s[d]) + b1 )
// 6 kernels: count -> scanoffs (lookback scan, all-resident) -> place ->
// gemm(+cfac) -> agg -> vred+out.
// count/place block mapping is CHUNK-MAJOR (c = bid&31): a chunk's 8
// slice-blocks share bid%8 -> one XCD -> chunk edges fetched once per XCD.
// (Round-9 slice-major experiment: +24us, chunk re-fetch 8x dominates any
// col-write line-ownership gain. Reverted.)

#define NCHUNK 32
#define LOG_NCHUNK 5
#define NSLICE 8
#define SLICE_MAX 6272   // LDS hist capacity; N <= 8*6272
#define SORT_T 1024      // threads for count/place
#define ZN 200           // zero-state ints: zagg[196] + cnt

typedef float v2f __attribute__((ext_vector_type(2)));

__device__ inline void fma4(float4& c, float a, const float4& b) {
    c.x = fmaf(a, b.x, c.x); c.y = fmaf(a, b.y, c.y);
    c.z = fmaf(a, b.z, c.z); c.w = fmaf(a, b.w, c.w);
}

// pack 4 floats -> 4 x fp8 e4m3 in one uint
__device__ inline unsigned pk_fp8(float a, float b, float c, float d) {
    int p = __builtin_amdgcn_cvt_pk_fp8_f32(a, b, 0, false);
    p = __builtin_amdgcn_cvt_pk_fp8_f32(c, d, p, true);
    return (unsigned)p;
}

// ---- K1: per-(chunk,slice) dst histogram via LDS; block 0 zeroes scan state ----
__launch_bounds__(SORT_T)
__global__ void k_count(const int* __restrict__ dst, int* __restrict__ partial,
                        int* __restrict__ zst, int N, int E, int chunkE, int sliceN) {
    if (blockIdx.x == 0) {
        for (int j = threadIdx.x; j < ZN; j += SORT_T) zst[j] = 0;
    }
    int c = blockIdx.x & (NCHUNK - 1), s = blockIdx.x >> LOG_NCHUNK;
    int nbase = s * sliceN;
    __shared__ int hist[SLICE_MAX];
    for (int j = threadIdx.x; j < sliceN; j += SORT_T) hist[j] = 0;
    __syncthreads();
    int e0 = c * chunkE, e1 = min(e0 + chunkE, E);
    int ne = e1 - e0;
    const int4* d4 = (const int4*)(dst + e0);
    int n4 = ne >> 2;
    for (int i = threadIdx.x; i < n4; i += SORT_T) {
        int4 d = d4[i];
        unsigned q;
        q = (unsigned)(d.x - nbase); if (q < (unsigned)sliceN) atomicAdd(&hist[q], 1);
        q = (unsigned)(d.y - nbase); if (q < (unsigned)sliceN) atomicAdd(&hist[q], 1);
        q = (unsigned)(d.z - nbase); if (q < (unsigned)sliceN) atomicAdd(&hist[q], 1);
        q = (unsigned)(d.w - nbase); if (q < (unsigned)sliceN) atomicAdd(&hist[q], 1);
    }
    if (threadIdx.x < (ne & 3)) {
        int d = dst[e0 + (n4 << 2) + threadIdx.x];
        unsigned q = (unsigned)(d - nbase);
        if (q < (unsigned)sliceN) atomicAdd(&hist[q], 1);
    }
    __syncthreads();
    for (int j = threadIdx.x; j < sliceN; j += SORT_T) {
        int n = nbase + j;
        if (n < N) partial[(size_t)c * N + n] = hist[j];
    }
}

// ---- K2: deg-sum -> dinv; all-resident lookback scan -> rowptr;
//      partial counts -> absolute offsets ----
__launch_bounds__(256)
__global__ void k_scanoffs(int* __restrict__ partial, float* __restrict__ dinv,
                           int* __restrict__ zagg, int* __restrict__ rowptr,
                           int N, int E) {
    int tid = threadIdx.x;
    int b = blockIdx.x;
    int n = b * 256 + tid;
    int deg = 0;
    if (n < N) {
        #pragma unroll
        for (int c = 0; c < NCHUNK; ++c) deg += partial[(size_t)c * N + n];
        dinv[n] = rsqrtf((float)(deg + 1));
    }
    __shared__ int sh[256];
    sh[tid] = deg;
    __syncthreads();
    for (int off = 1; off < 256; off <<= 1) {
        int t = (tid >= off) ? sh[tid - off] : 0;
        __syncthreads();
        sh[tid] += t;
        __syncthreads();
    }
    int incl = sh[tid];
    int btot = sh[255];
    if (tid == 0) atomicExch(&zagg[b], btot + 1);   // publish (sentinel 0 = not ready)
    __shared__ int s_off;
    if (tid == 0) s_off = 0;
    __syncthreads();
    if (tid < b) {   // all blocks co-resident (196 <= 256 CUs) -> no deadlock
        int v;
        while ((v = atomicAdd(&zagg[tid], 0)) == 0) __builtin_amdgcn_s_sleep(1);
        atomicAdd(&s_off, v - 1);
    }
    __syncthreads();
    int run = s_off + incl - deg;   // global exclusive prefix
    if (n < N) {
        rowptr[n] = run;
        #pragma unroll
        for (int c = 0; c < NCHUNK; ++c) {
            size_t ix = (size_t)c * N + n;
            int t = partial[ix];
            partial[ix] = run;
            run += t;
        }
    }
    if (b == 0 && tid == 0) rowptr[N] = E;
}

// ---- K3: place edges into col via LDS cursors; rsum partials into offs (dead) ----
__launch_bounds__(SORT_T)
__global__ void k_place(const int* __restrict__ src, const int* __restrict__ dst,
                        const float* __restrict__ dinv, int* __restrict__ offs,
                        int* __restrict__ col, int N, int E, int chunkE, int sliceN) {
    int c = blockIdx.x & (NCHUNK - 1), s = blockIdx.x >> LOG_NCHUNK;
    int nbase = s * sliceN;
    __shared__ int cur[SLICE_MAX];
    __shared__ float rs[SLICE_MAX];
    for (int j = threadIdx.x; j < sliceN; j += SORT_T) {
        int n = nbase + j;
        cur[j] = (n < N) ? offs[(size_t)c * N + n] : 0;
        rs[j] = 0.f;
    }
    __syncthreads();
    int e0 = c * chunkE, e1 = min(e0 + chunkE, E);
    int ne = e1 - e0;
    const int4* s4 = (const int4*)(src + e0);
    const int4* d4 = (const int4*)(dst + e0);
    int n4 = ne >> 2;
    for (int i = threadIdx.x; i < n4; i += SORT_T) {
        int4 sv = s4[i];
        int4 dv = d4[i];
        unsigned qd, qs;
        qd = (unsigned)(dv.x - nbase);
        if (qd < (unsigned)sliceN) { int p = atomicAdd(&cur[qd], 1); col[p] = sv.x; }
        qs = (unsigned)(sv.x - nbase);
        if (qs < (unsigned)sliceN) atomicAdd(&rs[qs], dinv[dv.x]);
        qd = (unsigned)(dv.y - nbase);
        if (qd < (unsigned)sliceN) { int p = atomicAdd(&cur[qd], 1); col[p] = sv.y; }
        qs = (unsigned)(sv.y - nbase);
        if (qs < (unsigned)sliceN) atomicAdd(&rs[qs], dinv[dv.y]);
        qd = (unsigned)(dv.z - nbase);
        if (qd < (unsigned)sliceN) { int p = atomicAdd(&cur[qd], 1); col[p] = sv.z; }
        qs = (unsigned)(sv.z - nbase);
        if (qs < (unsigned)sliceN) atomicAdd(&rs[qs], dinv[dv.z]);
        qd = (unsigned)(dv.w - nbase);
        if (qd < (unsigned)sliceN) { int p = atomicAdd(&cur[qd], 1); col[p] = sv.w; }
        qs = (unsigned)(sv.w - nbase);
        if (qs < (unsigned)sliceN) atomicAdd(&rs[qs], dinv[dv.w]);
    }
    if (threadIdx.x < (ne & 3)) {
        int e = e0 + (n4 << 2) + threadIdx.x;
        int sv = src[e], dv = dst[e];
        unsigned qd = (unsigned)(dv - nbase);
        if (qd < (unsigned)sliceN) { int p = atomicAdd(&cur[qd], 1); col[p] = sv; }
        unsigned qs = (unsigned)(sv - nbase);
        if (qs < (unsigned)sliceN) atomicAdd(&rs[qs], dinv[dv]);
    }
    __syncthreads();
    float* prs = (float*)offs;   // offs[c][this slice] dead after load -> reuse
    for (int j = threadIdx.x; j < sliceN; j += SORT_T) {
        int n = nbase + j;
        if (n < N) prs[(size_t)c * N + n] = rs[j];
    }
}

// ---- K4: g = fp8(16*(x @ W1)*dinv[row]); fused cfac = dinv*(dinv+rsum) ----
__launch_bounds__(256)
__global__ void k_gemm(const float* __restrict__ x, const float* __restrict__ W1,
                       const float* __restrict__ dinv, const float* __restrict__ prs,
                       float* __restrict__ cfac, unsigned* __restrict__ g, int n) {
    __shared__ float Ws[128 * 96];
    int tid = threadIdx.x;
    {
        const float4* wsrc = (const float4*)W1;
        float4* wdst = (float4*)Ws;
        #pragma unroll
        for (int i = 0; i < 12; ++i) wdst[tid + 256 * i] = wsrc[tid + 256 * i];
    }
    // fused rsum->cfac for this block's 128 rows (overlaps staging)
    {
        int r = blockIdx.x * 128 + tid;
        if (tid < 128 && r < n) {
            float s = 0.f;
            #pragma unroll
            for (int c = 0; c < NCHUNK; ++c) s += prs[(size_t)c * n + r];
            float dv = dinv[r];
            cfac[r] = dv * (dv + s);
        }
    }
    __syncthreads();

    int tx = tid & 7;          // 8 col groups of 12
    int ty = tid >> 3;         // 32 row quads
    int rbase = blockIdx.x * 128 + ty * 4;
    const float4* xp[4];
    bool vr[4];
    #pragma unroll
    for (int i = 0; i < 4; ++i) {
        int r = rbase + i;
        vr[i] = r < n;
        xp[i] = (const float4*)(x + (size_t)(vr[i] ? r : 0) * 128);
    }

    float4 acc[4][3];
    #pragma unroll
    for (int i = 0; i < 4; ++i)
        #pragma unroll
        for (int j = 0; j < 3; ++j) acc[i][j] = make_float4(0.f, 0.f, 0.f, 0.f);

    #pragma unroll 2
    for (int k4 = 0; k4 < 32; ++k4) {
        float4 a0 = xp[0][k4];
        float4 a1 = xp[1][k4];
        float4 a2 = xp[2][k4];
        float4 a3 = xp[3][k4];
        #pragma unroll
        for (int kk = 0; kk < 4; ++kk) {
            const float* wrow = &Ws[(k4 * 4 + kk) * 96 + tx * 12];
            float4 b0 = *(const float4*)(wrow);
            float4 b1 = *(const float4*)(wrow + 4);
            float4 b2 = *(const float4*)(wrow + 8);
            float av0 = (kk == 0) ? a0.x : (kk == 1) ? a0.y : (kk == 2) ? a0.z : a0.w;
            float av1 = (kk == 0) ? a1.x : (kk == 1) ? a1.y : (kk == 2) ? a1.z : a1.w;
            float av2 = (kk == 0) ? a2.x : (kk == 1) ? a2.y : (kk == 2) ? a2.z : a2.w;
            float av3 = (kk == 0) ? a3.x : (kk == 1) ? a3.y : (kk == 2) ? a3.z : a3.w;
            fma4(acc[0][0], av0, b0); fma4(acc[0][1], av0, b1); fma4(acc[0][2], av0, b2);
            fma4(acc[1][0], av1, b0); fma4(acc[1][1], av1, b1); fma4(acc[1][2], av1, b2);
            fma4(acc[2][0], av2, b0); fma4(acc[2][1], av2, b1); fma4(acc[2][2], av2, b2);
            fma4(acc[3][0], av3, b0); fma4(acc[3][1], av3, b1); fma4(acc[3][2], av3, b2);
        }
    }

    #pragma unroll
    for (int i = 0; i < 4; ++i) {
        if (!vr[i]) continue;
        int r = rbase + i;
        float dv = dinv[r] * 16.f;      // x16 scale for fp8 dynamic range
        unsigned* o = g + (size_t)r * 24 + tx * 3;
        float4 t;
        t = acc[i][0]; o[0] = pk_fp8(t.x * dv, t.y * dv, t.z * dv, t.w * dv);
        t = acc[i][1]; o[1] = pk_fp8(t.x * dv, t.y * dv, t.z * dv, t.w * dv);
        t = acc[i][2]; o[2] = pk_fp8(t.x * dv, t.y * dv, t.z * dv, t.w * dv);
    }
}

// ---- K5: per-node fp8 gather + fused bias/relu/cfac + block partial of v ----
#define AGG_NODES 16
#define AGG_T (AGG_NODES * 24)
__launch_bounds__(AGG_T)
__global__ void k_agg(const unsigned* __restrict__ g1, const int* __restrict__ col,
                      const int* __restrict__ rowptr, const float* __restrict__ dinv,
                      const float* __restrict__ cfac, const float* __restrict__ b1,
                      float* __restrict__ v_part, int n) {
    int tid = threadIdx.x;
    int nl = tid / 24;
    int ch = tid % 24;        // uint chunk of the 24-uint row (4 fp8 each)
    int d = blockIdx.x * AGG_NODES + nl;

    __shared__ float4 sh[AGG_NODES][24];

    float4 contrib = make_float4(0.f, 0.f, 0.f, 0.f);
    if (d < n) {
        float dds = dinv[d] * 0.0625f;   // undo x16 storage scale
        int e0 = rowptr[d], e1 = rowptr[d + 1];
        float4 aA = make_float4(0.f, 0.f, 0.f, 0.f);
        float4 aB = make_float4(0.f, 0.f, 0.f, 0.f);
        int e = e0;
        for (; e + 4 <= e1; e += 4) {
            int s0 = col[e], s1 = col[e + 1], s2 = col[e + 2], s3 = col[e + 3];
            unsigned u0 = g1[(size_t)s0 * 24 + ch];
            unsigned u1 = g1[(size_t)s1 * 24 + ch];
            unsigned u2 = g1[(size_t)s2 * 24 + ch];
            unsigned u3 = g1[(size_t)s3 * 24 + ch];
            v2f f;
            f = __builtin_amdgcn_cvt_pk_f32_fp8(u0, false); aA.x += f.x; aA.y += f.y;
            f = __builtin_amdgcn_cvt_pk_f32_fp8(u0, true);  aA.z += f.x; aA.w += f.y;
            f = __builtin_amdgcn_cvt_pk_f32_fp8(u1, false); aB.x += f.x; aB.y += f.y;
            f = __builtin_amdgcn_cvt_pk_f32_fp8(u1, true);  aB.z += f.x; aB.w += f.y;
            f = __builtin_amdgcn_cvt_pk_f32_fp8(u2, false); aA.x += f.x; aA.y += f.y;
            f = __builtin_amdgcn_cvt_pk_f32_fp8(u2, true);  aA.z += f.x; aA.w += f.y;
            f = __builtin_amdgcn_cvt_pk_f32_fp8(u3, false); aB.x += f.x; aB.y += f.y;
            f = __builtin_amdgcn_cvt_pk_f32_fp8(u3, true);  aB.z += f.x; aB.w += f.y;
        }
        for (; e < e1; ++e) {
            unsigned u = g1[(size_t)col[e] * 24 + ch];
            v2f f;
            f = __builtin_amdgcn_cvt_pk_f32_fp8(u, false); aA.x += f.x; aA.y += f.y;
            f = __builtin_amdgcn_cvt_pk_f32_fp8(u, true);  aA.z += f.x; aA.w += f.y;
        }
        {   // analytic self-loop: g[d] joins the same sum
            unsigned u = g1[(size_t)d * 24 + ch];
            v2f f;
            f = __builtin_amdgcn_cvt_pk_f32_fp8(u, false); aA.x += f.x; aA.y += f.y;
            f = __builtin_amdgcn_cvt_pk_f32_fp8(u, true);  aA.z += f.x; aA.w += f.y;
        }
        float4 b1c = ((const float4*)b1)[ch];
        float cd = cfac[d];
        float hx = fmaxf(fmaf(dds, aA.x + aB.x, b1c.x), 0.f);
        float hy = fmaxf(fmaf(dds, aA.y + aB.y, b1c.y), 0.f);
        float hz = fmaxf(fmaf(dds, aA.z + aB.z, b1c.z), 0.f);
        float hw = fmaxf(fmaf(dds, aA.w + aB.w, b1c.w), 0.f);
        contrib = make_float4(cd * hx, cd * hy, cd * hz, cd * hw);
    }
    sh[nl][ch] = contrib;
    __syncthreads();
    #pragma unroll
    for (int off = 8; off >= 1; off >>= 1) {
        if (nl < off) {
            float4 a = sh[nl][ch];
            float4 b = sh[nl + off][ch];
            a.x += b.x; a.y += b.y; a.z += b.z; a.w += b.w;
            sh[nl][ch] = a;
        }
        __syncthreads();
    }
    if (tid < 24) {
        ((float4*)(v_part + (size_t)blockIdx.x * 96))[tid] = sh[0][tid];
    }
}

// ---- K6: v_part column-reduce; last block computes mu/logvar matvecs ----
__launch_bounds__(256)
__global__ void k_vredout(const float* __restrict__ vp, float* __restrict__ v,
                          int* __restrict__ cnt, int nb,
                          const float* __restrict__ Wmu, const float* __restrict__ bmu,
                          const float* __restrict__ Wlv, const float* __restrict__ blv,
                          float* __restrict__ out, float nN) {
    int j = blockIdx.x;   // 96 blocks
    int tid = threadIdx.x;
    float s = 0.f;
    for (int i = tid; i < nb; i += 256) s += vp[(size_t)i * 96 + j];
    __shared__ float sh[256];
    sh[tid] = s;
    __syncthreads();
    for (int off = 128; off; off >>= 1) {
        if (tid < off) sh[tid] += sh[tid + off];
        __syncthreads();
    }
    __shared__ int s_last;
    if (tid == 0) {
        atomicExch((unsigned*)&v[j], __float_as_uint(sh[0]));  // device-scope publish
        __threadfence();
        s_last = (atomicAdd(cnt, 1) == 95);
    }
    __syncthreads();
    if (!s_last) return;
    __shared__ float vv[96];
    if (tid < 96) vv[tid] = __uint_as_float(atomicAdd((unsigned*)&v[tid], 0u));
    __syncthreads();
    if (tid < 128) {
        const float* W = (tid < 64) ? Wmu : Wlv;
        const float* b = (tid < 64) ? bmu : blv;
        int jj = tid & 63;
        float acc = 0.f;
        #pragma unroll
        for (int k = 0; k < 96; ++k) acc = fmaf(vv[k], W[k * 64 + jj], acc);
        out[tid] = acc + nN * b[jj];
    }
}

extern "C" void kernel_launch(void* const* d_in, const int* in_sizes, int n_in,
                              void* d_out, int out_size, void* d_ws, size_t ws_size,
                              hipStream_t stream) {
    const float* x   = (const float*)d_in[0];
    const int*   ei  = (const int*)d_in[1];
    const float* W1  = (const float*)d_in[2];
    const float* b1  = (const float*)d_in[3];
    const float* Wmu = (const float*)d_in[4];
    const float* bmu = (const float*)d_in[5];
    const float* Wlv = (const float*)d_in[6];
    const float* blv = (const float*)d_in[7];
    float* out = (float*)d_out;

    const int N = in_sizes[0] / 128;   // 50000
    const int E = in_sizes[1] / 2;     // 800000
    const int* src = ei;
    const int* dst = ei + E;

    const int chunkE = (((E + NCHUNK - 1) / NCHUNK) + 3) & ~3;   // 25000
    const int sliceN = (N + NSLICE - 1) / NSLICE;                // 6250
    const int gN = (N + 255) / 256;                              // 196

    size_t off = 0;
    auto alloc = [&](size_t bytes) -> char* {
        off = (off + 255) & ~(size_t)255;
        char* p = (char*)d_ws + off;
        off += bytes;
        return p;
    };
    int*      partial = (int*)alloc((size_t)NCHUNK * N * 4);  // counts->offs->rsum partials
    int*      rowptr  = (int*)alloc((size_t)(N + 1) * 4);
    int*      col     = (int*)alloc((size_t)E * 4);
    float*    dinv    = (float*)alloc((size_t)N * 4);
    float*    cfac    = (float*)alloc((size_t)N * 4);
    int*      zst     = (int*)alloc((size_t)ZN * 4);          // zagg[196] + cnt
    unsigned* g       = (unsigned*)alloc((size_t)N * 96);     // fp8 e4m3, 24 uints/row
    const int nAggBlocks = (N + AGG_NODES - 1) / AGG_NODES;   // 3125
    float*    v_part  = (float*)alloc((size_t)nAggBlocks * 96 * 4);
    float*    v       = (float*)alloc(96 * 4);

    int* zagg = zst;          // [196]
    int* cnt  = zst + 196;    // [1]

    k_count<<<NCHUNK * NSLICE, SORT_T, 0, stream>>>(dst, partial, zst, N, E, chunkE, sliceN);
    k_scanoffs<<<gN, 256, 0, stream>>>(partial, dinv, zagg, rowptr, N, E);
    k_place<<<NCHUNK * NSLICE, SORT_T, 0, stream>>>(src, dst, dinv, partial, col, N, E, chunkE, sliceN);
    k_gemm<<<(N + 127) / 128, 256, 0, stream>>>(x, W1, dinv, (const float*)partial, cfac, g, N);
    k_agg<<<nAggBlocks, AGG_T, 0, stream>>>(g, col, rowptr, dinv, cfac, b1, v_part, N);
    k_vredout<<<96, 256, 0, stream>>>(v_part, v, cnt, nAggBlocks, Wmu, bmu, Wlv, blv, out, (float)N);
}

// Round 11
// 113.303 us; speedup vs baseline: 1.0327x; 1.0220x over previous
//
#include <hip/hip_runtime.h>
#include <hip/hip_fp16.h>

// GCN encoder, N=50000, E=800000, 128 -> 96 (relu) -> sum-pooled 64+64.
// Sum-pooled layer 2: out = (sum_u c[u]*h[u]) @ W + N*b,
//   c[u] = dinv[u]*(dinv[u] + rsum[u]),  rsum[u] = sum_{e: src=u} dinv[dst_e].
// Layer 1 with g[u] = (xW1)[u]*dinv[u]  (fp8 e4m3, x16 scale):
//   h[d] = relu( (dinv[d]/16)*(sum_{e->d} g_s[src] + g_s[d]) + b1 )
// 7 kernels: count -> degdinv -> offs -> place -> gemm(+cfac) -> agg -> vredout.
// NOTE (round-9/10 lesson): NO device-scope spin-wait scans. The lookback
// scan's polling atomics congested the coherent point (+23us). Scan is split
// into degdinv (publish blocksum) + offs (plain reduce of blocksum) instead.
// col is ushort (N < 65536): halves CSR write+read traffic.

#define NCHUNK 32
#define LOG_NCHUNK 5
#define NSLICE 8
#define SLICE_MAX 6272   // LDS hist capacity; N <= 8*6272
#define SORT_T 1024      // threads for count/place

typedef float v2f __attribute__((ext_vector_type(2)));

__device__ inline void fma4(float4& c, float a, const float4& b) {
    c.x = fmaf(a, b.x, c.x); c.y = fmaf(a, b.y, c.y);
    c.z = fmaf(a, b.z, c.z); c.w = fmaf(a, b.w, c.w);
}

// pack 4 floats -> 4 x fp8 e4m3 in one uint
__device__ inline unsigned pk_fp8(float a, float b, float c, float d) {
    int p = __builtin_amdgcn_cvt_pk_fp8_f32(a, b, 0, false);
    p = __builtin_amdgcn_cvt_pk_fp8_f32(c, d, p, true);
    return (unsigned)p;
}

// ---- K1: per-(chunk,slice) dst histogram via LDS; block 0 zeroes cnt ----
// c = bid & 31 (chunk-major): a chunk's 8 slice-blocks share one XCD's L2.
__launch_bounds__(SORT_T)
__global__ void k_count(const int* __restrict__ dst, int* __restrict__ partial,
                        int* __restrict__ cnt, int N, int E, int chunkE, int sliceN) {
    if (blockIdx.x == 0 && threadIdx.x == 0) *cnt = 0;
    int c = blockIdx.x & (NCHUNK - 1), s = blockIdx.x >> LOG_NCHUNK;
    int nbase = s * sliceN;
    __shared__ int hist[SLICE_MAX];
    for (int j = threadIdx.x; j < sliceN; j += SORT_T) hist[j] = 0;
    __syncthreads();
    int e0 = c * chunkE, e1 = min(e0 + chunkE, E);
    int ne = e1 - e0;
    const int4* d4 = (const int4*)(dst + e0);
    int n4 = ne >> 2;
    for (int i = threadIdx.x; i < n4; i += SORT_T) {
        int4 d = d4[i];
        unsigned q;
        q = (unsigned)(d.x - nbase); if (q < (unsigned)sliceN) atomicAdd(&hist[q], 1);
        q = (unsigned)(d.y - nbase); if (q < (unsigned)sliceN) atomicAdd(&hist[q], 1);
        q = (unsigned)(d.z - nbase); if (q < (unsigned)sliceN) atomicAdd(&hist[q], 1);
        q = (unsigned)(d.w - nbase); if (q < (unsigned)sliceN) atomicAdd(&hist[q], 1);
    }
    if (threadIdx.x < (ne & 3)) {
        int d = dst[e0 + (n4 << 2) + threadIdx.x];
        unsigned q = (unsigned)(d - nbase);
        if (q < (unsigned)sliceN) atomicAdd(&hist[q], 1);
    }
    __syncthreads();
    for (int j = threadIdx.x; j < sliceN; j += SORT_T) {
        int n = nbase + j;
        if (n < N) partial[(size_t)c * N + n] = hist[j];
    }
}

// ---- K2: deg = sum over chunks; dinv; per-block sum of deg ----
__launch_bounds__(256)
__global__ void k_degdinv(const int* __restrict__ partial, int* __restrict__ deg,
                          float* __restrict__ dinv, int* __restrict__ blocksum, int N) {
    int tid = threadIdx.x;
    int n = blockIdx.x * 256 + tid;
    int s = 0;
    if (n < N) {
        #pragma unroll
        for (int c = 0; c < NCHUNK; ++c) s += partial[(size_t)c * N + n];
        deg[n] = s;
        dinv[n] = rsqrtf((float)(s + 1));
    }
    __shared__ int sh[256];
    sh[tid] = s;
    __syncthreads();
    #pragma unroll
    for (int off = 128; off; off >>= 1) {
        if (tid < off) sh[tid] += sh[tid + off];
        __syncthreads();
    }
    if (tid == 0) blocksum[blockIdx.x] = sh[0];
}

// ---- K3: per-block scan of deg -> rowptr; partial counts -> abs offsets ----
// Block offset = plain reduce of blocksum[b < bid] (nb <= 256), no spinning.
__launch_bounds__(256)
__global__ void k_offs(int* __restrict__ partial, const int* __restrict__ deg,
                       const int* __restrict__ blocksum, int* __restrict__ rowptr,
                       int N, int E, int nb) {
    int tid = threadIdx.x;
    __shared__ int sh[256];
    int bs = (tid < nb && tid < (int)blockIdx.x) ? blocksum[tid] : 0;
    sh[tid] = bs;
    __syncthreads();
    #pragma unroll
    for (int off = 128; off; off >>= 1) {
        if (tid < off) sh[tid] += sh[tid + off];
        __syncthreads();
    }
    int blockoff = sh[0];
    __syncthreads();
    int n = blockIdx.x * 256 + tid;
    int v = (n < N) ? deg[n] : 0;
    sh[tid] = v;
    __syncthreads();
    for (int off = 1; off < 256; off <<= 1) {
        int t = (tid >= off) ? sh[tid - off] : 0;
        __syncthreads();
        sh[tid] += t;
        __syncthreads();
    }
    int run = blockoff + sh[tid] - v;   // exclusive prefix
    if (n < N) {
        rowptr[n] = run;
        #pragma unroll
        for (int c = 0; c < NCHUNK; ++c) {
            size_t ix = (size_t)c * N + n;
            int t = partial[ix];
            partial[ix] = run;
            run += t;
        }
    }
    if (blockIdx.x == 0 && tid == 0) rowptr[N] = E;
}

// ---- K4: place edges into col (ushort) via LDS cursors; rsum partials into offs ----
__launch_bounds__(SORT_T)
__global__ void k_place(const int* __restrict__ src, const int* __restrict__ dst,
                        const float* __restrict__ dinv, int* __restrict__ offs,
                        unsigned short* __restrict__ col, int N, int E, int chunkE, int sliceN) {
    int c = blockIdx.x & (NCHUNK - 1), s = blockIdx.x >> LOG_NCHUNK;
    int nbase = s * sliceN;
    __shared__ int cur[SLICE_MAX];
    __shared__ float rs[SLICE_MAX];
    for (int j = threadIdx.x; j < sliceN; j += SORT_T) {
        int n = nbase + j;
        cur[j] = (n < N) ? offs[(size_t)c * N + n] : 0;
        rs[j] = 0.f;
    }
    __syncthreads();
    int e0 = c * chunkE, e1 = min(e0 + chunkE, E);
    int ne = e1 - e0;
    const int4* s4 = (const int4*)(src + e0);
    const int4* d4 = (const int4*)(dst + e0);
    int n4 = ne >> 2;
    for (int i = threadIdx.x; i < n4; i += SORT_T) {
        int4 sv = s4[i];
        int4 dv = d4[i];
        unsigned qd, qs;
        qd = (unsigned)(dv.x - nbase);
        if (qd < (unsigned)sliceN) { int p = atomicAdd(&cur[qd], 1); col[p] = (unsigned short)sv.x; }
        qs = (unsigned)(sv.x - nbase);
        if (qs < (unsigned)sliceN) atomicAdd(&rs[qs], dinv[dv.x]);
        qd = (unsigned)(dv.y - nbase);
        if (qd < (unsigned)sliceN) { int p = atomicAdd(&cur[qd], 1); col[p] = (unsigned short)sv.y; }
        qs = (unsigned)(sv.y - nbase);
        if (qs < (unsigned)sliceN) atomicAdd(&rs[qs], dinv[dv.y]);
        qd = (unsigned)(dv.z - nbase);
        if (qd < (unsigned)sliceN) { int p = atomicAdd(&cur[qd], 1); col[p] = (unsigned short)sv.z; }
        qs = (unsigned)(sv.z - nbase);
        if (qs < (unsigned)sliceN) atomicAdd(&rs[qs], dinv[dv.z]);
        qd = (unsigned)(dv.w - nbase);
        if (qd < (unsigned)sliceN) { int p = atomicAdd(&cur[qd], 1); col[p] = (unsigned short)sv.w; }
        qs = (unsigned)(sv.w - nbase);
        if (qs < (unsigned)sliceN) atomicAdd(&rs[qs], dinv[dv.w]);
    }
    if (threadIdx.x < (ne & 3)) {
        int e = e0 + (n4 << 2) + threadIdx.x;
        int sv = src[e], dv = dst[e];
        unsigned qd = (unsigned)(dv - nbase);
        if (qd < (unsigned)sliceN) { int p = atomicAdd(&cur[qd], 1); col[p] = (unsigned short)sv; }
        unsigned qs = (unsigned)(sv - nbase);
        if (qs < (unsigned)sliceN) atomicAdd(&rs[qs], dinv[dv]);
    }
    __syncthreads();
    float* prs = (float*)offs;   // offs[c][this slice] dead after load -> reuse
    for (int j = threadIdx.x; j < sliceN; j += SORT_T) {
        int n = nbase + j;
        if (n < N) prs[(size_t)c * N + n] = rs[j];
    }
}

// ---- K5: g = fp8(16*(x @ W1)*dinv[row]); fused cfac = dinv*(dinv+rsum) ----
__launch_bounds__(256)
__global__ void k_gemm(const float* __restrict__ x, const float* __restrict__ W1,
                       const float* __restrict__ dinv, const float* __restrict__ prs,
                       float* __restrict__ cfac, unsigned* __restrict__ g, int n) {
    __shared__ float Ws[128 * 96];
    int tid = threadIdx.x;
    {
        const float4* wsrc = (const float4*)W1;
        float4* wdst = (float4*)Ws;
        #pragma unroll
        for (int i = 0; i < 12; ++i) wdst[tid + 256 * i] = wsrc[tid + 256 * i];
    }
    // fused rsum->cfac for this block's 128 rows (overlaps staging)
    {
        int r = blockIdx.x * 128 + tid;
        if (tid < 128 && r < n) {
            float s = 0.f;
            #pragma unroll
            for (int c = 0; c < NCHUNK; ++c) s += prs[(size_t)c * n + r];
            float dv = dinv[r];
            cfac[r] = dv * (dv + s);
        }
    }
    __syncthreads();

    int tx = tid & 7;          // 8 col groups of 12
    int ty = tid >> 3;         // 32 row quads
    int rbase = blockIdx.x * 128 + ty * 4;
    const float4* xp[4];
    bool vr[4];
    #pragma unroll
    for (int i = 0; i < 4; ++i) {
        int r = rbase + i;
        vr[i] = r < n;
        xp[i] = (const float4*)(x + (size_t)(vr[i] ? r : 0) * 128);
    }

    float4 acc[4][3];
    #pragma unroll
    for (int i = 0; i < 4; ++i)
        #pragma unroll
        for (int j = 0; j < 3; ++j) acc[i][j] = make_float4(0.f, 0.f, 0.f, 0.f);

    #pragma unroll 2
    for (int k4 = 0; k4 < 32; ++k4) {
        float4 a0 = xp[0][k4];
        float4 a1 = xp[1][k4];
        float4 a2 = xp[2][k4];
        float4 a3 = xp[3][k4];
        #pragma unroll
        for (int kk = 0; kk < 4; ++kk) {
            const float* wrow = &Ws[(k4 * 4 + kk) * 96 + tx * 12];
            float4 b0 = *(const float4*)(wrow);
            float4 b1 = *(const float4*)(wrow + 4);
            float4 b2 = *(const float4*)(wrow + 8);
            float av0 = (kk == 0) ? a0.x : (kk == 1) ? a0.y : (kk == 2) ? a0.z : a0.w;
            float av1 = (kk == 0) ? a1.x : (kk == 1) ? a1.y : (kk == 2) ? a1.z : a1.w;
            float av2 = (kk == 0) ? a2.x : (kk == 1) ? a2.y : (kk == 2) ? a2.z : a2.w;
            float av3 = (kk == 0) ? a3.x : (kk == 1) ? a3.y : (kk == 2) ? a3.z : a3.w;
            fma4(acc[0][0], av0, b0); fma4(acc[0][1], av0, b1); fma4(acc[0][2], av0, b2);
            fma4(acc[1][0], av1, b0); fma4(acc[1][1], av1, b1); fma4(acc[1][2], av1, b2);
            fma4(acc[2][0], av2, b0); fma4(acc[2][1], av2, b1); fma4(acc[2][2], av2, b2);
            fma4(acc[3][0], av3, b0); fma4(acc[3][1], av3, b1); fma4(acc[3][2], av3, b2);
        }
    }

    #pragma unroll
    for (int i = 0; i < 4; ++i) {
        if (!vr[i]) continue;
        int r = rbase + i;
        float dv = dinv[r] * 16.f;      // x16 scale for fp8 dynamic range
        unsigned* o = g + (size_t)r * 24 + tx * 3;
        float4 t;
        t = acc[i][0]; o[0] = pk_fp8(t.x * dv, t.y * dv, t.z * dv, t.w * dv);
        t = acc[i][1]; o[1] = pk_fp8(t.x * dv, t.y * dv, t.z * dv, t.w * dv);
        t = acc[i][2]; o[2] = pk_fp8(t.x * dv, t.y * dv, t.z * dv, t.w * dv);
    }
}

// ---- K6: per-node fp8 gather + fused bias/relu/cfac + block partial of v ----
#define AGG_NODES 16
#define AGG_T (AGG_NODES * 24)
__launch_bounds__(AGG_T)
__global__ void k_agg(const unsigned* __restrict__ g1, const unsigned short* __restrict__ col,
                      const int* __restrict__ rowptr, const float* __restrict__ dinv,
                      const float* __restrict__ cfac, const float* __restrict__ b1,
                      float* __restrict__ v_part, int n) {
    int tid = threadIdx.x;
    int nl = tid / 24;
    int ch = tid % 24;        // uint chunk of the 24-uint row (4 fp8 each)
    int d = blockIdx.x * AGG_NODES + nl;

    __shared__ float4 sh[AGG_NODES][24];

    float4 contrib = make_float4(0.f, 0.f, 0.f, 0.f);
    if (d < n) {
        float dds = dinv[d] * 0.0625f;   // undo x16 storage scale
        int e0 = rowptr[d], e1 = rowptr[d + 1];
        float4 aA = make_float4(0.f, 0.f, 0.f, 0.f);
        float4 aB = make_float4(0.f, 0.f, 0.f, 0.f);
        int e = e0;
        for (; e + 4 <= e1; e += 4) {
            int s0 = col[e], s1 = col[e + 1], s2 = col[e + 2], s3 = col[e + 3];
            unsigned u0 = g1[(size_t)s0 * 24 + ch];
            unsigned u1 = g1[(size_t)s1 * 24 + ch];
            unsigned u2 = g1[(size_t)s2 * 24 + ch];
            unsigned u3 = g1[(size_t)s3 * 24 + ch];
            v2f f;
            f = __builtin_amdgcn_cvt_pk_f32_fp8(u0, false); aA.x += f.x; aA.y += f.y;
            f = __builtin_amdgcn_cvt_pk_f32_fp8(u0, true);  aA.z += f.x; aA.w += f.y;
            f = __builtin_amdgcn_cvt_pk_f32_fp8(u1, false); aB.x += f.x; aB.y += f.y;
            f = __builtin_amdgcn_cvt_pk_f32_fp8(u1, true);  aB.z += f.x; aB.w += f.y;
            f = __builtin_amdgcn_cvt_pk_f32_fp8(u2, false); aA.x += f.x; aA.y += f.y;
            f = __builtin_amdgcn_cvt_pk_f32_fp8(u2, true);  aA.z += f.x; aA.w += f.y;
            f = __builtin_amdgcn_cvt_pk_f32_fp8(u3, false); aB.x += f.x; aB.y += f.y;
            f = __builtin_amdgcn_cvt_pk_f32_fp8(u3, true);  aB.z += f.x; aB.w += f.y;
        }
        for (; e < e1; ++e) {
            unsigned u = g1[(size_t)col[e] * 24 + ch];
            v2f f;
            f = __builtin_amdgcn_cvt_pk_f32_fp8(u, false); aA.x += f.x; aA.y += f.y;
            f = __builtin_amdgcn_cvt_pk_f32_fp8(u, true);  aA.z += f.x; aA.w += f.y;
        }
        {   // analytic self-loop: g[d] joins the same sum
            unsigned u = g1[(size_t)d * 24 + ch];
            v2f f;
            f = __builtin_amdgcn_cvt_pk_f32_fp8(u, false); aA.x += f.x; aA.y += f.y;
            f = __builtin_amdgcn_cvt_pk_f32_fp8(u, true);  aA.z += f.x; aA.w += f.y;
        }
        float4 b1c = ((const float4*)b1)[ch];
        float cd = cfac[d];
        float hx = fmaxf(fmaf(dds, aA.x + aB.x, b1c.x), 0.f);
        float hy = fmaxf(fmaf(dds, aA.y + aB.y, b1c.y), 0.f);
        float hz = fmaxf(fmaf(dds, aA.z + aB.z, b1c.z), 0.f);
        float hw = fmaxf(fmaf(dds, aA.w + aB.w, b1c.w), 0.f);
        contrib = make_float4(cd * hx, cd * hy, cd * hz, cd * hw);
    }
    sh[nl][ch] = contrib;
    __syncthreads();
    #pragma unroll
    for (int off = 8; off >= 1; off >>= 1) {
        if (nl < off) {
            float4 a = sh[nl][ch];
            float4 b = sh[nl + off][ch];
            a.x += b.x; a.y += b.y; a.z += b.z; a.w += b.w;
            sh[nl][ch] = a;
        }
        __syncthreads();
    }
    if (tid < 24) {
        ((float4*)(v_part + (size_t)blockIdx.x * 96))[tid] = sh[0][tid];
    }
}

// ---- K7: v_part column-reduce; last block computes mu/logvar matvecs ----
__launch_bounds__(256)
__global__ void k_vredout(const float* __restrict__ vp, float* __restrict__ v,
                          int* __restrict__ cnt, int nb,
                          const float* __restrict__ Wmu, const float* __restrict__ bmu,
                          const float* __restrict__ Wlv, const float* __restrict__ blv,
                          float* __restrict__ out, float nN) {
    int j = blockIdx.x;   // 96 blocks
    int tid = threadIdx.x;
    float s = 0.f;
    for (int i = tid; i < nb; i += 256) s += vp[(size_t)i * 96 + j];
    __shared__ float sh[256];
    sh[tid] = s;
    __syncthreads();
    for (int off = 128; off; off >>= 1) {
        if (tid < off) sh[tid] += sh[tid + off];
        __syncthreads();
    }
    __shared__ int s_last;
    if (tid == 0) {
        atomicExch((unsigned*)&v[j], __float_as_uint(sh[0]));  // device-scope publish
        __threadfence();
        s_last = (atomicAdd(cnt, 1) == 95);
    }
    __syncthreads();
    if (!s_last) return;
    __shared__ float vv[96];
    if (tid < 96) vv[tid] = __uint_as_float(atomicAdd((unsigned*)&v[tid], 0u));
    __syncthreads();
    if (tid < 128) {
        const float* W = (tid < 64) ? Wmu : Wlv;
        const float* b = (tid < 64) ? bmu : blv;
        int jj = tid & 63;
        float acc = 0.f;
        #pragma unroll
        for (int k = 0; k < 96; ++k) acc = fmaf(vv[k], W[k * 64 + jj], acc);
        out[tid] = acc + nN * b[jj];
    }
}

extern "C" void kernel_launch(void* const* d_in, const int* in_sizes, int n_in,
                              void* d_out, int out_size, void* d_ws, size_t ws_size,
                              hipStream_t stream) {
    const float* x   = (const float*)d_in[0];
    const int*   ei  = (const int*)d_in[1];
    const float* W1  = (const float*)d_in[2];
    const float* b1  = (const float*)d_in[3];
    const float* Wmu = (const float*)d_in[4];
    const float* bmu = (const float*)d_in[5];
    const float* Wlv = (const float*)d_in[6];
    const float* blv = (const float*)d_in[7];
    float* out = (float*)d_out;

    const int N = in_sizes[0] / 128;   // 50000 (< 65536: col fits ushort)
    const int E = in_sizes[1] / 2;     // 800000
    const int* src = ei;
    const int* dst = ei + E;

    const int chunkE = (((E + NCHUNK - 1) / NCHUNK) + 3) & ~3;   // 25000
    const int sliceN = (N + NSLICE - 1) / NSLICE;                // 6250
    const int gN = (N + 255) / 256;                              // 196

    size_t off = 0;
    auto alloc = [&](size_t bytes) -> char* {
        off = (off + 255) & ~(size_t)255;
        char* p = (char*)d_ws + off;
        off += bytes;
        return p;
    };
    int*            partial  = (int*)alloc((size_t)NCHUNK * N * 4);  // counts->offs->rsum partials
    int*            rowptr   = (int*)alloc((size_t)(N + 1) * 4);
    unsigned short* col      = (unsigned short*)alloc((size_t)E * 2);
    int*            deg      = (int*)alloc((size_t)N * 4);
    float*          dinv     = (float*)alloc((size_t)N * 4);
    float*          cfac     = (float*)alloc((size_t)N * 4);
    int*            blocksum = (int*)alloc((size_t)gN * 4);
    int*            cnt      = (int*)alloc(256);
    unsigned*       g        = (unsigned*)alloc((size_t)N * 96);    // fp8 e4m3, 24 uints/row
    const int nAggBlocks = (N + AGG_NODES - 1) / AGG_NODES;         // 3125
    float*          v_part   = (float*)alloc((size_t)nAggBlocks * 96 * 4);
    float*          v        = (float*)alloc(96 * 4);

    k_count<<<NCHUNK * NSLICE, SORT_T, 0, stream>>>(dst, partial, cnt, N, E, chunkE, sliceN);
    k_degdinv<<<gN, 256, 0, stream>>>(partial, deg, dinv, blocksum, N);
    k_offs<<<gN, 256, 0, stream>>>(partial, deg, blocksum, rowptr, N, E, gN);
    k_place<<<NCHUNK * NSLICE, SORT_T, 0, stream>>>(src, dst, dinv, partial, col, N, E, chunkE, sliceN);
    k_gemm<<<(N + 127) / 128, 256, 0, stream>>>(x, W1, dinv, (const float*)partial, cfac, g, N);
    k_agg<<<nAggBlocks, AGG_T, 0, stream>>>(g, col, rowptr, dinv, cfac, b1, v_part, N);
    k_vredout<<<96, 256, 0, stream>>>(v_part, v, cnt, nAggBlocks, Wmu, bmu, Wlv, blv, out, (float)N);
}

// Round 12
// 111.862 us; speedup vs baseline: 1.0460x; 1.0129x over previous
//
#include <hip/hip_runtime.h>
#include <hip/hip_fp16.h>

// GCN encoder, N=50000, E=800000, 128 -> 96 (relu) -> sum-pooled 64+64.
// Sum-pooled layer 2: out = (sum_u c[u]*h[u]) @ W + N*b,
//   c[u] = dinv[u]*(dinv[u] + rsum[u]),  rsum[u] = sum_{e: src=u} dinv[dst_e].
// Layer 1 with g[u] = (xW1)[u]*dinv[u]  (fp8 e4m3, x16 scale):
//   h[d] = relu( (dinv[d]/16)*(sum_{e->d} g_s[src] + g_s[d]) + b1 )
// EXACT round-7 structure (measured 92.8us) + k_vredout fusion only.
// Lessons pinned: NO spin-wait scans (atomic storm, +20us); col stays INT
// (ushort doubled cross-XCD false sharing on the scatter, +20us); place/count
// are chunk-major 1024-thread blocks.

#define NCHUNK 32
#define LOG_NCHUNK 5
#define NSLICE 8
#define SLICE_MAX 6272   // LDS hist capacity; N <= 8*6272
#define SORT_T 1024      // threads for count/place

typedef float v2f __attribute__((ext_vector_type(2)));

__device__ inline void fma4(float4& c, float a, const float4& b) {
    c.x = fmaf(a, b.x, c.x); c.y = fmaf(a, b.y, c.y);
    c.z = fmaf(a, b.z, c.z); c.w = fmaf(a, b.w, c.w);
}

// pack 4 floats -> 4 x fp8 e4m3 in one uint
__device__ inline unsigned pk_fp8(float a, float b, float c, float d) {
    int p = __builtin_amdgcn_cvt_pk_fp8_f32(a, b, 0, false);
    p = __builtin_amdgcn_cvt_pk_fp8_f32(c, d, p, true);
    return (unsigned)p;
}

// ---- K1: per-(chunk,slice) dst histogram via LDS; block 0 zeroes cnt ----
// c = bid & 31 (chunk-major): a chunk's 8 slice-blocks share one XCD's L2.
__launch_bounds__(SORT_T)
__global__ void k_count(const int* __restrict__ dst, int* __restrict__ partial,
                        int* __restrict__ cnt, int N, int E, int chunkE, int sliceN) {
    if (blockIdx.x == 0 && threadIdx.x == 0) *cnt = 0;
    int c = blockIdx.x & (NCHUNK - 1), s = blockIdx.x >> LOG_NCHUNK;
    int nbase = s * sliceN;
    __shared__ int hist[SLICE_MAX];
    for (int j = threadIdx.x; j < sliceN; j += SORT_T) hist[j] = 0;
    __syncthreads();
    int e0 = c * chunkE, e1 = min(e0 + chunkE, E);
    int ne = e1 - e0;
    const int4* d4 = (const int4*)(dst + e0);
    int n4 = ne >> 2;
    for (int i = threadIdx.x; i < n4; i += SORT_T) {
        int4 d = d4[i];
        unsigned q;
        q = (unsigned)(d.x - nbase); if (q < (unsigned)sliceN) atomicAdd(&hist[q], 1);
        q = (unsigned)(d.y - nbase); if (q < (unsigned)sliceN) atomicAdd(&hist[q], 1);
        q = (unsigned)(d.z - nbase); if (q < (unsigned)sliceN) atomicAdd(&hist[q], 1);
        q = (unsigned)(d.w - nbase); if (q < (unsigned)sliceN) atomicAdd(&hist[q], 1);
    }
    if (threadIdx.x < (ne & 3)) {
        int d = dst[e0 + (n4 << 2) + threadIdx.x];
        unsigned q = (unsigned)(d - nbase);
        if (q < (unsigned)sliceN) atomicAdd(&hist[q], 1);
    }
    __syncthreads();
    for (int j = threadIdx.x; j < sliceN; j += SORT_T) {
        int n = nbase + j;
        if (n < N) partial[(size_t)c * N + n] = hist[j];
    }
}

// ---- K2: deg = sum over chunks; dinv; per-block sum of deg ----
__launch_bounds__(256)
__global__ void k_degdinv(const int* __restrict__ partial, int* __restrict__ deg,
                          float* __restrict__ dinv, int* __restrict__ blocksum, int N) {
    int tid = threadIdx.x;
    int n = blockIdx.x * 256 + tid;
    int s = 0;
    if (n < N) {
        #pragma unroll
        for (int c = 0; c < NCHUNK; ++c) s += partial[(size_t)c * N + n];
        deg[n] = s;
        dinv[n] = rsqrtf((float)(s + 1));
    }
    __shared__ int sh[256];
    sh[tid] = s;
    __syncthreads();
    #pragma unroll
    for (int off = 128; off; off >>= 1) {
        if (tid < off) sh[tid] += sh[tid + off];
        __syncthreads();
    }
    if (tid == 0) blocksum[blockIdx.x] = sh[0];
}

// ---- K3: per-block scan of deg -> rowptr; partial counts -> abs offsets ----
// Block offset = plain reduce of blocksum[b < bid] (nb <= 256), no spinning.
__launch_bounds__(256)
__global__ void k_offs(int* __restrict__ partial, const int* __restrict__ deg,
                       const int* __restrict__ blocksum, int* __restrict__ rowptr,
                       int N, int E, int nb) {
    int tid = threadIdx.x;
    __shared__ int sh[256];
    int bs = (tid < nb && tid < (int)blockIdx.x) ? blocksum[tid] : 0;
    sh[tid] = bs;
    __syncthreads();
    #pragma unroll
    for (int off = 128; off; off >>= 1) {
        if (tid < off) sh[tid] += sh[tid + off];
        __syncthreads();
    }
    int blockoff = sh[0];
    __syncthreads();
    int n = blockIdx.x * 256 + tid;
    int v = (n < N) ? deg[n] : 0;
    sh[tid] = v;
    __syncthreads();
    for (int off = 1; off < 256; off <<= 1) {
        int t = (tid >= off) ? sh[tid - off] : 0;
        __syncthreads();
        sh[tid] += t;
        __syncthreads();
    }
    int run = blockoff + sh[tid] - v;   // exclusive prefix
    if (n < N) {
        rowptr[n] = run;
        #pragma unroll
        for (int c = 0; c < NCHUNK; ++c) {
            size_t ix = (size_t)c * N + n;
            int t = partial[ix];
            partial[ix] = run;
            run += t;
        }
    }
    if (blockIdx.x == 0 && tid == 0) rowptr[N] = E;
}

// ---- K4: place edges into col (int) via LDS cursors; rsum partials into offs ----
__launch_bounds__(SORT_T)
__global__ void k_place(const int* __restrict__ src, const int* __restrict__ dst,
                        const float* __restrict__ dinv, int* __restrict__ offs,
                        int* __restrict__ col, int N, int E, int chunkE, int sliceN) {
    int c = blockIdx.x & (NCHUNK - 1), s = blockIdx.x >> LOG_NCHUNK;
    int nbase = s * sliceN;
    __shared__ int cur[SLICE_MAX];
    __shared__ float rs[SLICE_MAX];
    for (int j = threadIdx.x; j < sliceN; j += SORT_T) {
        int n = nbase + j;
        cur[j] = (n < N) ? offs[(size_t)c * N + n] : 0;
        rs[j] = 0.f;
    }
    __syncthreads();
    int e0 = c * chunkE, e1 = min(e0 + chunkE, E);
    int ne = e1 - e0;
    const int4* s4 = (const int4*)(src + e0);
    const int4* d4 = (const int4*)(dst + e0);
    int n4 = ne >> 2;
    for (int i = threadIdx.x; i < n4; i += SORT_T) {
        int4 sv = s4[i];
        int4 dv = d4[i];
        unsigned qd, qs;
        qd = (unsigned)(dv.x - nbase);
        if (qd < (unsigned)sliceN) { int p = atomicAdd(&cur[qd], 1); col[p] = sv.x; }
        qs = (unsigned)(sv.x - nbase);
        if (qs < (unsigned)sliceN) atomicAdd(&rs[qs], dinv[dv.x]);
        qd = (unsigned)(dv.y - nbase);
        if (qd < (unsigned)sliceN) { int p = atomicAdd(&cur[qd], 1); col[p] = sv.y; }
        qs = (unsigned)(sv.y - nbase);
        if (qs < (unsigned)sliceN) atomicAdd(&rs[qs], dinv[dv.y]);
        qd = (unsigned)(dv.z - nbase);
        if (qd < (unsigned)sliceN) { int p = atomicAdd(&cur[qd], 1); col[p] = sv.z; }
        qs = (unsigned)(sv.z - nbase);
        if (qs < (unsigned)sliceN) atomicAdd(&rs[qs], dinv[dv.z]);
        qd = (unsigned)(dv.w - nbase);
        if (qd < (unsigned)sliceN) { int p = atomicAdd(&cur[qd], 1); col[p] = sv.w; }
        qs = (unsigned)(sv.w - nbase);
        if (qs < (unsigned)sliceN) atomicAdd(&rs[qs], dinv[dv.w]);
    }
    if (threadIdx.x < (ne & 3)) {
        int e = e0 + (n4 << 2) + threadIdx.x;
        int sv = src[e], dv = dst[e];
        unsigned qd = (unsigned)(dv - nbase);
        if (qd < (unsigned)sliceN) { int p = atomicAdd(&cur[qd], 1); col[p] = sv; }
        unsigned qs = (unsigned)(sv - nbase);
        if (qs < (unsigned)sliceN) atomicAdd(&rs[qs], dinv[dv]);
    }
    __syncthreads();
    float* prs = (float*)offs;   // offs[c][this slice] dead after load -> reuse
    for (int j = threadIdx.x; j < sliceN; j += SORT_T) {
        int n = nbase + j;
        if (n < N) prs[(size_t)c * N + n] = rs[j];
    }
}

// ---- K5: g = fp8(16*(x @ W1)*dinv[row]); fused cfac = dinv*(dinv+rsum) ----
__launch_bounds__(256)
__global__ void k_gemm(const float* __restrict__ x, const float* __restrict__ W1,
                       const float* __restrict__ dinv, const float* __restrict__ prs,
                       float* __restrict__ cfac, unsigned* __restrict__ g, int n) {
    __shared__ float Ws[128 * 96];
    int tid = threadIdx.x;
    {
        const float4* wsrc = (const float4*)W1;
        float4* wdst = (float4*)Ws;
        #pragma unroll
        for (int i = 0; i < 12; ++i) wdst[tid + 256 * i] = wsrc[tid + 256 * i];
    }
    // fused rsum->cfac for this block's 128 rows (overlaps staging)
    {
        int r = blockIdx.x * 128 + tid;
        if (tid < 128 && r < n) {
            float s = 0.f;
            #pragma unroll
            for (int c = 0; c < NCHUNK; ++c) s += prs[(size_t)c * n + r];
            float dv = dinv[r];
            cfac[r] = dv * (dv + s);
        }
    }
    __syncthreads();

    int tx = tid & 7;          // 8 col groups of 12
    int ty = tid >> 3;         // 32 row quads
    int rbase = blockIdx.x * 128 + ty * 4;
    const float4* xp[4];
    bool vr[4];
    #pragma unroll
    for (int i = 0; i < 4; ++i) {
        int r = rbase + i;
        vr[i] = r < n;
        xp[i] = (const float4*)(x + (size_t)(vr[i] ? r : 0) * 128);
    }

    float4 acc[4][3];
    #pragma unroll
    for (int i = 0; i < 4; ++i)
        #pragma unroll
        for (int j = 0; j < 3; ++j) acc[i][j] = make_float4(0.f, 0.f, 0.f, 0.f);

    #pragma unroll 2
    for (int k4 = 0; k4 < 32; ++k4) {
        float4 a0 = xp[0][k4];
        float4 a1 = xp[1][k4];
        float4 a2 = xp[2][k4];
        float4 a3 = xp[3][k4];
        #pragma unroll
        for (int kk = 0; kk < 4; ++kk) {
            const float* wrow = &Ws[(k4 * 4 + kk) * 96 + tx * 12];
            float4 b0 = *(const float4*)(wrow);
            float4 b1 = *(const float4*)(wrow + 4);
            float4 b2 = *(const float4*)(wrow + 8);
            float av0 = (kk == 0) ? a0.x : (kk == 1) ? a0.y : (kk == 2) ? a0.z : a0.w;
            float av1 = (kk == 0) ? a1.x : (kk == 1) ? a1.y : (kk == 2) ? a1.z : a1.w;
            float av2 = (kk == 0) ? a2.x : (kk == 1) ? a2.y : (kk == 2) ? a2.z : a2.w;
            float av3 = (kk == 0) ? a3.x : (kk == 1) ? a3.y : (kk == 2) ? a3.z : a3.w;
            fma4(acc[0][0], av0, b0); fma4(acc[0][1], av0, b1); fma4(acc[0][2], av0, b2);
            fma4(acc[1][0], av1, b0); fma4(acc[1][1], av1, b1); fma4(acc[1][2], av1, b2);
            fma4(acc[2][0], av2, b0); fma4(acc[2][1], av2, b1); fma4(acc[2][2], av2, b2);
            fma4(acc[3][0], av3, b0); fma4(acc[3][1], av3, b1); fma4(acc[3][2], av3, b2);
        }
    }

    #pragma unroll
    for (int i = 0; i < 4; ++i) {
        if (!vr[i]) continue;
        int r = rbase + i;
        float dv = dinv[r] * 16.f;      // x16 scale for fp8 dynamic range
        unsigned* o = g + (size_t)r * 24 + tx * 3;
        float4 t;
        t = acc[i][0]; o[0] = pk_fp8(t.x * dv, t.y * dv, t.z * dv, t.w * dv);
        t = acc[i][1]; o[1] = pk_fp8(t.x * dv, t.y * dv, t.z * dv, t.w * dv);
        t = acc[i][2]; o[2] = pk_fp8(t.x * dv, t.y * dv, t.z * dv, t.w * dv);
    }
}

// ---- K6: per-node fp8 gather + fused bias/relu/cfac + block partial of v ----
#define AGG_NODES 16
#define AGG_T (AGG_NODES * 24)
__launch_bounds__(AGG_T)
__global__ void k_agg(const unsigned* __restrict__ g1, const int* __restrict__ col,
                      const int* __restrict__ rowptr, const float* __restrict__ dinv,
                      const float* __restrict__ cfac, const float* __restrict__ b1,
                      float* __restrict__ v_part, int n) {
    int tid = threadIdx.x;
    int nl = tid / 24;
    int ch = tid % 24;        // uint chunk of the 24-uint row (4 fp8 each)
    int d = blockIdx.x * AGG_NODES + nl;

    __shared__ float4 sh[AGG_NODES][24];

    float4 contrib = make_float4(0.f, 0.f, 0.f, 0.f);
    if (d < n) {
        float dds = dinv[d] * 0.0625f;   // undo x16 storage scale
        int e0 = rowptr[d], e1 = rowptr[d + 1];
        float4 aA = make_float4(0.f, 0.f, 0.f, 0.f);
        float4 aB = make_float4(0.f, 0.f, 0.f, 0.f);
        int e = e0;
        for (; e + 4 <= e1; e += 4) {
            int s0 = col[e], s1 = col[e + 1], s2 = col[e + 2], s3 = col[e + 3];
            unsigned u0 = g1[(size_t)s0 * 24 + ch];
            unsigned u1 = g1[(size_t)s1 * 24 + ch];
            unsigned u2 = g1[(size_t)s2 * 24 + ch];
            unsigned u3 = g1[(size_t)s3 * 24 + ch];
            v2f f;
            f = __builtin_amdgcn_cvt_pk_f32_fp8(u0, false); aA.x += f.x; aA.y += f.y;
            f = __builtin_amdgcn_cvt_pk_f32_fp8(u0, true);  aA.z += f.x; aA.w += f.y;
            f = __builtin_amdgcn_cvt_pk_f32_fp8(u1, false); aB.x += f.x; aB.y += f.y;
            f = __builtin_amdgcn_cvt_pk_f32_fp8(u1, true);  aB.z += f.x; aB.w += f.y;
            f = __builtin_amdgcn_cvt_pk_f32_fp8(u2, false); aA.x += f.x; aA.y += f.y;
            f = __builtin_amdgcn_cvt_pk_f32_fp8(u2, true);  aA.z += f.x; aA.w += f.y;
            f = __builtin_amdgcn_cvt_pk_f32_fp8(u3, false); aB.x += f.x; aB.y += f.y;
            f = __builtin_amdgcn_cvt_pk_f32_fp8(u3, true);  aB.z += f.x; aB.w += f.y;
        }
        for (; e < e1; ++e) {
            unsigned u = g1[(size_t)col[e] * 24 + ch];
            v2f f;
            f = __builtin_amdgcn_cvt_pk_f32_fp8(u, false); aA.x += f.x; aA.y += f.y;
            f = __builtin_amdgcn_cvt_pk_f32_fp8(u, true);  aA.z += f.x; aA.w += f.y;
        }
        {   // analytic self-loop: g[d] joins the same sum
            unsigned u = g1[(size_t)d * 24 + ch];
            v2f f;
            f = __builtin_amdgcn_cvt_pk_f32_fp8(u, false); aA.x += f.x; aA.y += f.y;
            f = __builtin_amdgcn_cvt_pk_f32_fp8(u, true);  aA.z += f.x; aA.w += f.y;
        }
        float4 b1c = ((const float4*)b1)[ch];
        float cd = cfac[d];
        float hx = fmaxf(fmaf(dds, aA.x + aB.x, b1c.x), 0.f);
        float hy = fmaxf(fmaf(dds, aA.y + aB.y, b1c.y), 0.f);
        float hz = fmaxf(fmaf(dds, aA.z + aB.z, b1c.z), 0.f);
        float hw = fmaxf(fmaf(dds, aA.w + aB.w, b1c.w), 0.f);
        contrib = make_float4(cd * hx, cd * hy, cd * hz, cd * hw);
    }
    sh[nl][ch] = contrib;
    __syncthreads();
    #pragma unroll
    for (int off = 8; off >= 1; off >>= 1) {
        if (nl < off) {
            float4 a = sh[nl][ch];
            float4 b = sh[nl + off][ch];
            a.x += b.x; a.y += b.y; a.z += b.z; a.w += b.w;
            sh[nl][ch] = a;
        }
        __syncthreads();
    }
    if (tid < 24) {
        ((float4*)(v_part + (size_t)blockIdx.x * 96))[tid] = sh[0][tid];
    }
}

// ---- K7: v_part column-reduce; last block computes mu/logvar matvecs ----
__launch_bounds__(256)
__global__ void k_vredout(const float* __restrict__ vp, float* __restrict__ v,
                          int* __restrict__ cnt, int nb,
                          const float* __restrict__ Wmu, const float* __restrict__ bmu,
                          const float* __restrict__ Wlv, const float* __restrict__ blv,
                          float* __restrict__ out, float nN) {
    int j = blockIdx.x;   // 96 blocks
    int tid = threadIdx.x;
    float s = 0.f;
    for (int i = tid; i < nb; i += 256) s += vp[(size_t)i * 96 + j];
    __shared__ float sh[256];
    sh[tid] = s;
    __syncthreads();
    for (int off = 128; off; off >>= 1) {
        if (tid < off) sh[tid] += sh[tid + off];
        __syncthreads();
    }
    __shared__ int s_last;
    if (tid == 0) {
        atomicExch((unsigned*)&v[j], __float_as_uint(sh[0]));  // device-scope publish
        __threadfence();
        s_last = (atomicAdd(cnt, 1) == 95);
    }
    __syncthreads();
    if (!s_last) return;
    __shared__ float vv[96];
    if (tid < 96) vv[tid] = __uint_as_float(atomicAdd((unsigned*)&v[tid], 0u));
    __syncthreads();
    if (tid < 128) {
        const float* W = (tid < 64) ? Wmu : Wlv;
        const float* b = (tid < 64) ? bmu : blv;
        int jj = tid & 63;
        float acc = 0.f;
        #pragma unroll
        for (int k = 0; k < 96; ++k) acc = fmaf(vv[k], W[k * 64 + jj], acc);
        out[tid] = acc + nN * b[jj];
    }
}

extern "C" void kernel_launch(void* const* d_in, const int* in_sizes, int n_in,
                              void* d_out, int out_size, void* d_ws, size_t ws_size,
                              hipStream_t stream) {
    const float* x   = (const float*)d_in[0];
    const int*   ei  = (const int*)d_in[1];
    const float* W1  = (const float*)d_in[2];
    const float* b1  = (const float*)d_in[3];
    const float* Wmu = (const float*)d_in[4];
    const float* bmu = (const float*)d_in[5];
    const float* Wlv = (const float*)d_in[6];
    const float* blv = (const float*)d_in[7];
    float* out = (float*)d_out;

    const int N = in_sizes[0] / 128;   // 50000
    const int E = in_sizes[1] / 2;     // 800000
    const int* src = ei;
    const int* dst = ei + E;

    const int chunkE = (((E + NCHUNK - 1) / NCHUNK) + 3) & ~3;   // 25000
    const int sliceN = (N + NSLICE - 1) / NSLICE;                // 6250
    const int gN = (N + 255) / 256;                              // 196

    size_t off = 0;
    auto alloc = [&](size_t bytes) -> char* {
        off = (off + 255) & ~(size_t)255;
        char* p = (char*)d_ws + off;
        off += bytes;
        return p;
    };
    int*      partial  = (int*)alloc((size_t)NCHUNK * N * 4);  // counts->offs->rsum partials
    int*      rowptr   = (int*)alloc((size_t)(N + 1) * 4);
    int*      col      = (int*)alloc((size_t)E * 4);
    int*      deg      = (int*)alloc((size_t)N * 4);
    float*    dinv     = (float*)alloc((size_t)N * 4);
    float*    cfac     = (float*)alloc((size_t)N * 4);
    int*      blocksum = (int*)alloc((size_t)gN * 4);
    int*      cnt      = (int*)alloc(256);
    unsigned* g        = (unsigned*)alloc((size_t)N * 96);     // fp8 e4m3, 24 uints/row
    const int nAggBlocks = (N + AGG_NODES - 1) / AGG_NODES;    // 3125
    float*    v_part   = (float*)alloc((size_t)nAggBlocks * 96 * 4);
    float*    v        = (float*)alloc(96 * 4);

    k_count<<<NCHUNK * NSLICE, SORT_T, 0, stream>>>(dst, partial, cnt, N, E, chunkE, sliceN);
    k_degdinv<<<gN, 256, 0, stream>>>(partial, deg, dinv, blocksum, N);
    k_offs<<<gN, 256, 0, stream>>>(partial, deg, blocksum, rowptr, N, E, gN);
    k_place<<<NCHUNK * NSLICE, SORT_T, 0, stream>>>(src, dst, dinv, partial, col, N, E, chunkE, sliceN);
    k_gemm<<<(N + 127) / 128, 256, 0, stream>>>(x, W1, dinv, (const float*)partial, cfac, g, N);
    k_agg<<<nAggBlocks, AGG_T, 0, stream>>>(g, col, rowptr, dinv, cfac, b1, v_part, N);
    k_vredout<<<96, 256, 0, stream>>>(v_part, v, cnt, nAggBlocks, Wmu, bmu, Wlv, blv, out, (float)N);
}

// Round 13
// 92.998 us; speedup vs baseline: 1.2582x; 1.2028x over previous
//
#include <hip/hip_runtime.h>
#include <hip/hip_fp16.h>

// GCN encoder, N=50000, E=800000, 128 -> 96 (relu) -> sum-pooled 64+64.
// Sum-pooled layer 2: out = (sum_u c[u]*h[u]) @ W + N*b,
//   c[u] = dinv[u]*(dinv[u] + rsum[u]),  rsum[u] = sum_{e: src=u} dinv[dst_e].
// Layer 1 with g[u] = (xW1)[u]*dinv[u]  (fp8 e4m3, x16 scale):
//   h[d] = relu( (dinv[d]/16)*(sum_{e->d} g_s[src] + g_s[d]) + b1 )
// EXACT round-7 structure (measured 92.8us). 8 kernels:
// count -> degdinv -> offs -> place -> gemm(+cfac) -> agg -> vred -> out.
// Lessons pinned (rounds 9-12, all ~+20us each):
//  * NO device-scope spin-wait scans (atomic storm at coherent point).
//  * NO per-block __threadfence/atomic-publish fusions (k_vredout: 42us —
//    agent fences force per-XCD L2 writeback on gfx950). Kernel boundary
//    sync is CHEAPER than 96 in-kernel fences.
//  * col stays INT; count/place chunk-major (c=bid&31) 1024-thread blocks.

#define NCHUNK 32
#define LOG_NCHUNK 5
#define NSLICE 8
#define SLICE_MAX 6272   // LDS hist capacity; N <= 8*6272
#define SORT_T 1024      // threads for count/place

typedef float v2f __attribute__((ext_vector_type(2)));

__device__ inline void fma4(float4& c, float a, const float4& b) {
    c.x = fmaf(a, b.x, c.x); c.y = fmaf(a, b.y, c.y);
    c.z = fmaf(a, b.z, c.z); c.w = fmaf(a, b.w, c.w);
}

// pack 4 floats -> 4 x fp8 e4m3 in one uint
__device__ inline unsigned pk_fp8(float a, float b, float c, float d) {
    int p = __builtin_amdgcn_cvt_pk_fp8_f32(a, b, 0, false);
    p = __builtin_amdgcn_cvt_pk_fp8_f32(c, d, p, true);
    return (unsigned)p;
}

// ---- K1: per-(chunk,slice) dst histogram via LDS ----
// c = bid & 31 (chunk-major): a chunk's 8 slice-blocks share one XCD's L2.
__launch_bounds__(SORT_T)
__global__ void k_count(const int* __restrict__ dst, int* __restrict__ partial,
                        int N, int E, int chunkE, int sliceN) {
    int c = blockIdx.x & (NCHUNK - 1), s = blockIdx.x >> LOG_NCHUNK;
    int nbase = s * sliceN;
    __shared__ int hist[SLICE_MAX];
    for (int j = threadIdx.x; j < sliceN; j += SORT_T) hist[j] = 0;
    __syncthreads();
    int e0 = c * chunkE, e1 = min(e0 + chunkE, E);
    int ne = e1 - e0;
    const int4* d4 = (const int4*)(dst + e0);
    int n4 = ne >> 2;
    for (int i = threadIdx.x; i < n4; i += SORT_T) {
        int4 d = d4[i];
        unsigned q;
        q = (unsigned)(d.x - nbase); if (q < (unsigned)sliceN) atomicAdd(&hist[q], 1);
        q = (unsigned)(d.y - nbase); if (q < (unsigned)sliceN) atomicAdd(&hist[q], 1);
        q = (unsigned)(d.z - nbase); if (q < (unsigned)sliceN) atomicAdd(&hist[q], 1);
        q = (unsigned)(d.w - nbase); if (q < (unsigned)sliceN) atomicAdd(&hist[q], 1);
    }
    if (threadIdx.x < (ne & 3)) {
        int d = dst[e0 + (n4 << 2) + threadIdx.x];
        unsigned q = (unsigned)(d - nbase);
        if (q < (unsigned)sliceN) atomicAdd(&hist[q], 1);
    }
    __syncthreads();
    for (int j = threadIdx.x; j < sliceN; j += SORT_T) {
        int n = nbase + j;
        if (n < N) partial[(size_t)c * N + n] = hist[j];
    }
}

// ---- K2: deg = sum over chunks; dinv; per-block sum of deg ----
__launch_bounds__(256)
__global__ void k_degdinv(const int* __restrict__ partial, int* __restrict__ deg,
                          float* __restrict__ dinv, int* __restrict__ blocksum, int N) {
    int tid = threadIdx.x;
    int n = blockIdx.x * 256 + tid;
    int s = 0;
    if (n < N) {
        #pragma unroll
        for (int c = 0; c < NCHUNK; ++c) s += partial[(size_t)c * N + n];
        deg[n] = s;
        dinv[n] = rsqrtf((float)(s + 1));
    }
    __shared__ int sh[256];
    sh[tid] = s;
    __syncthreads();
    #pragma unroll
    for (int off = 128; off; off >>= 1) {
        if (tid < off) sh[tid] += sh[tid + off];
        __syncthreads();
    }
    if (tid == 0) blocksum[blockIdx.x] = sh[0];
}

// ---- K3: per-block scan of deg -> rowptr; partial counts -> abs offsets ----
// Block offset = plain reduce of blocksum[b < bid] (nb <= 256), no spinning.
__launch_bounds__(256)
__global__ void k_offs(int* __restrict__ partial, const int* __restrict__ deg,
                       const int* __restrict__ blocksum, int* __restrict__ rowptr,
                       int N, int E, int nb) {
    int tid = threadIdx.x;
    __shared__ int sh[256];
    int bs = (tid < nb && tid < (int)blockIdx.x) ? blocksum[tid] : 0;
    sh[tid] = bs;
    __syncthreads();
    #pragma unroll
    for (int off = 128; off; off >>= 1) {
        if (tid < off) sh[tid] += sh[tid + off];
        __syncthreads();
    }
    int blockoff = sh[0];
    __syncthreads();
    int n = blockIdx.x * 256 + tid;
    int v = (n < N) ? deg[n] : 0;
    sh[tid] = v;
    __syncthreads();
    for (int off = 1; off < 256; off <<= 1) {
        int t = (tid >= off) ? sh[tid - off] : 0;
        __syncthreads();
        sh[tid] += t;
        __syncthreads();
    }
    int run = blockoff + sh[tid] - v;   // exclusive prefix
    if (n < N) {
        rowptr[n] = run;
        #pragma unroll
        for (int c = 0; c < NCHUNK; ++c) {
            size_t ix = (size_t)c * N + n;
            int t = partial[ix];
            partial[ix] = run;
            run += t;
        }
    }
    if (blockIdx.x == 0 && tid == 0) rowptr[N] = E;
}

// ---- K4: place edges into col (int) via LDS cursors; rsum partials into offs ----
__launch_bounds__(SORT_T)
__global__ void k_place(const int* __restrict__ src, const int* __restrict__ dst,
                        const float* __restrict__ dinv, int* __restrict__ offs,
                        int* __restrict__ col, int N, int E, int chunkE, int sliceN) {
    int c = blockIdx.x & (NCHUNK - 1), s = blockIdx.x >> LOG_NCHUNK;
    int nbase = s * sliceN;
    __shared__ int cur[SLICE_MAX];
    __shared__ float rs[SLICE_MAX];
    for (int j = threadIdx.x; j < sliceN; j += SORT_T) {
        int n = nbase + j;
        cur[j] = (n < N) ? offs[(size_t)c * N + n] : 0;
        rs[j] = 0.f;
    }
    __syncthreads();
    int e0 = c * chunkE, e1 = min(e0 + chunkE, E);
    int ne = e1 - e0;
    const int4* s4 = (const int4*)(src + e0);
    const int4* d4 = (const int4*)(dst + e0);
    int n4 = ne >> 2;
    for (int i = threadIdx.x; i < n4; i += SORT_T) {
        int4 sv = s4[i];
        int4 dv = d4[i];
        unsigned qd, qs;
        qd = (unsigned)(dv.x - nbase);
        if (qd < (unsigned)sliceN) { int p = atomicAdd(&cur[qd], 1); col[p] = sv.x; }
        qs = (unsigned)(sv.x - nbase);
        if (qs < (unsigned)sliceN) atomicAdd(&rs[qs], dinv[dv.x]);
        qd = (unsigned)(dv.y - nbase);
        if (qd < (unsigned)sliceN) { int p = atomicAdd(&cur[qd], 1); col[p] = sv.y; }
        qs = (unsigned)(sv.y - nbase);
        if (qs < (unsigned)sliceN) atomicAdd(&rs[qs], dinv[dv.y]);
        qd = (unsigned)(dv.z - nbase);
        if (qd < (unsigned)sliceN) { int p = atomicAdd(&cur[qd], 1); col[p] = sv.z; }
        qs = (unsigned)(sv.z - nbase);
        if (qs < (unsigned)sliceN) atomicAdd(&rs[qs], dinv[dv.z]);
        qd = (unsigned)(dv.w - nbase);
        if (qd < (unsigned)sliceN) { int p = atomicAdd(&cur[qd], 1); col[p] = sv.w; }
        qs = (unsigned)(sv.w - nbase);
        if (qs < (unsigned)sliceN) atomicAdd(&rs[qs], dinv[dv.w]);
    }
    if (threadIdx.x < (ne & 3)) {
        int e = e0 + (n4 << 2) + threadIdx.x;
        int sv = src[e], dv = dst[e];
        unsigned qd = (unsigned)(dv - nbase);
        if (qd < (unsigned)sliceN) { int p = atomicAdd(&cur[qd], 1); col[p] = sv; }
        unsigned qs = (unsigned)(sv - nbase);
        if (qs < (unsigned)sliceN) atomicAdd(&rs[qs], dinv[dv]);
    }
    __syncthreads();
    float* prs = (float*)offs;   // offs[c][this slice] dead after load -> reuse
    for (int j = threadIdx.x; j < sliceN; j += SORT_T) {
        int n = nbase + j;
        if (n < N) prs[(size_t)c * N + n] = rs[j];
    }
}

// ---- K5: g = fp8(16*(x @ W1)*dinv[row]); fused cfac = dinv*(dinv+rsum) ----
__launch_bounds__(256)
__global__ void k_gemm(const float* __restrict__ x, const float* __restrict__ W1,
                       const float* __restrict__ dinv, const float* __restrict__ prs,
                       float* __restrict__ cfac, unsigned* __restrict__ g, int n) {
    __shared__ float Ws[128 * 96];
    int tid = threadIdx.x;
    {
        const float4* wsrc = (const float4*)W1;
        float4* wdst = (float4*)Ws;
        #pragma unroll
        for (int i = 0; i < 12; ++i) wdst[tid + 256 * i] = wsrc[tid + 256 * i];
    }
    // fused rsum->cfac for this block's 128 rows (overlaps staging)
    {
        int r = blockIdx.x * 128 + tid;
        if (tid < 128 && r < n) {
            float s = 0.f;
            #pragma unroll
            for (int c = 0; c < NCHUNK; ++c) s += prs[(size_t)c * n + r];
            float dv = dinv[r];
            cfac[r] = dv * (dv + s);
        }
    }
    __syncthreads();

    int tx = tid & 7;          // 8 col groups of 12
    int ty = tid >> 3;         // 32 row quads
    int rbase = blockIdx.x * 128 + ty * 4;
    const float4* xp[4];
    bool vr[4];
    #pragma unroll
    for (int i = 0; i < 4; ++i) {
        int r = rbase + i;
        vr[i] = r < n;
        xp[i] = (const float4*)(x + (size_t)(vr[i] ? r : 0) * 128);
    }

    float4 acc[4][3];
    #pragma unroll
    for (int i = 0; i < 4; ++i)
        #pragma unroll
        for (int j = 0; j < 3; ++j) acc[i][j] = make_float4(0.f, 0.f, 0.f, 0.f);

    #pragma unroll 2
    for (int k4 = 0; k4 < 32; ++k4) {
        float4 a0 = xp[0][k4];
        float4 a1 = xp[1][k4];
        float4 a2 = xp[2][k4];
        float4 a3 = xp[3][k4];
        #pragma unroll
        for (int kk = 0; kk < 4; ++kk) {
            const float* wrow = &Ws[(k4 * 4 + kk) * 96 + tx * 12];
            float4 b0 = *(const float4*)(wrow);
            float4 b1 = *(const float4*)(wrow + 4);
            float4 b2 = *(const float4*)(wrow + 8);
            float av0 = (kk == 0) ? a0.x : (kk == 1) ? a0.y : (kk == 2) ? a0.z : a0.w;
            float av1 = (kk == 0) ? a1.x : (kk == 1) ? a1.y : (kk == 2) ? a1.z : a1.w;
            float av2 = (kk == 0) ? a2.x : (kk == 1) ? a2.y : (kk == 2) ? a2.z : a2.w;
            float av3 = (kk == 0) ? a3.x : (kk == 1) ? a3.y : (kk == 2) ? a3.z : a3.w;
            fma4(acc[0][0], av0, b0); fma4(acc[0][1], av0, b1); fma4(acc[0][2], av0, b2);
            fma4(acc[1][0], av1, b0); fma4(acc[1][1], av1, b1); fma4(acc[1][2], av1, b2);
            fma4(acc[2][0], av2, b0); fma4(acc[2][1], av2, b1); fma4(acc[2][2], av2, b2);
            fma4(acc[3][0], av3, b0); fma4(acc[3][1], av3, b1); fma4(acc[3][2], av3, b2);
        }
    }

    #pragma unroll
    for (int i = 0; i < 4; ++i) {
        if (!vr[i]) continue;
        int r = rbase + i;
        float dv = dinv[r] * 16.f;      // x16 scale for fp8 dynamic range
        unsigned* o = g + (size_t)r * 24 + tx * 3;
        float4 t;
        t = acc[i][0]; o[0] = pk_fp8(t.x * dv, t.y * dv, t.z * dv, t.w * dv);
        t = acc[i][1]; o[1] = pk_fp8(t.x * dv, t.y * dv, t.z * dv, t.w * dv);
        t = acc[i][2]; o[2] = pk_fp8(t.x * dv, t.y * dv, t.z * dv, t.w * dv);
    }
}

// ---- K6: per-node fp8 gather + fused bias/relu/cfac + block partial of v ----
#define AGG_NODES 16
#define AGG_T (AGG_NODES * 24)
__launch_bounds__(AGG_T)
__global__ void k_agg(const unsigned* __restrict__ g1, const int* __restrict__ col,
                      const int* __restrict__ rowptr, const float* __restrict__ dinv,
                      const float* __restrict__ cfac, const float* __restrict__ b1,
                      float* __restrict__ v_part, int n) {
    int tid = threadIdx.x;
    int nl = tid / 24;
    int ch = tid % 24;        // uint chunk of the 24-uint row (4 fp8 each)
    int d = blockIdx.x * AGG_NODES + nl;

    __shared__ float4 sh[AGG_NODES][24];

    float4 contrib = make_float4(0.f, 0.f, 0.f, 0.f);
    if (d < n) {
        float dds = dinv[d] * 0.0625f;   // undo x16 storage scale
        int e0 = rowptr[d], e1 = rowptr[d + 1];
        float4 aA = make_float4(0.f, 0.f, 0.f, 0.f);
        float4 aB = make_float4(0.f, 0.f, 0.f, 0.f);
        int e = e0;
        for (; e + 4 <= e1; e += 4) {
            int s0 = col[e], s1 = col[e + 1], s2 = col[e + 2], s3 = col[e + 3];
            unsigned u0 = g1[(size_t)s0 * 24 + ch];
            unsigned u1 = g1[(size_t)s1 * 24 + ch];
            unsigned u2 = g1[(size_t)s2 * 24 + ch];
            unsigned u3 = g1[(size_t)s3 * 24 + ch];
            v2f f;
            f = __builtin_amdgcn_cvt_pk_f32_fp8(u0, false); aA.x += f.x; aA.y += f.y;
            f = __builtin_amdgcn_cvt_pk_f32_fp8(u0, true);  aA.z += f.x; aA.w += f.y;
            f = __builtin_amdgcn_cvt_pk_f32_fp8(u1, false); aB.x += f.x; aB.y += f.y;
            f = __builtin_amdgcn_cvt_pk_f32_fp8(u1, true);  aB.z += f.x; aB.w += f.y;
            f = __builtin_amdgcn_cvt_pk_f32_fp8(u2, false); aA.x += f.x; aA.y += f.y;
            f = __builtin_amdgcn_cvt_pk_f32_fp8(u2, true);  aA.z += f.x; aA.w += f.y;
            f = __builtin_amdgcn_cvt_pk_f32_fp8(u3, false); aB.x += f.x; aB.y += f.y;
            f = __builtin_amdgcn_cvt_pk_f32_fp8(u3, true);  aB.z += f.x; aB.w += f.y;
        }
        for (; e < e1; ++e) {
            unsigned u = g1[(size_t)col[e] * 24 + ch];
            v2f f;
            f = __builtin_amdgcn_cvt_pk_f32_fp8(u, false); aA.x += f.x; aA.y += f.y;
            f = __builtin_amdgcn_cvt_pk_f32_fp8(u, true);  aA.z += f.x; aA.w += f.y;
        }
        {   // analytic self-loop: g[d] joins the same sum
            unsigned u = g1[(size_t)d * 24 + ch];
            v2f f;
            f = __builtin_amdgcn_cvt_pk_f32_fp8(u, false); aA.x += f.x; aA.y += f.y;
            f = __builtin_amdgcn_cvt_pk_f32_fp8(u, true);  aA.z += f.x; aA.w += f.y;
        }
        float4 b1c = ((const float4*)b1)[ch];
        float cd = cfac[d];
        float hx = fmaxf(fmaf(dds, aA.x + aB.x, b1c.x), 0.f);
        float hy = fmaxf(fmaf(dds, aA.y + aB.y, b1c.y), 0.f);
        float hz = fmaxf(fmaf(dds, aA.z + aB.z, b1c.z), 0.f);
        float hw = fmaxf(fmaf(dds, aA.w + aB.w, b1c.w), 0.f);
        contrib = make_float4(cd * hx, cd * hy, cd * hz, cd * hw);
    }
    sh[nl][ch] = contrib;
    __syncthreads();
    #pragma unroll
    for (int off = 8; off >= 1; off >>= 1) {
        if (nl < off) {
            float4 a = sh[nl][ch];
            float4 b = sh[nl + off][ch];
            a.x += b.x; a.y += b.y; a.z += b.z; a.w += b.w;
            sh[nl][ch] = a;
        }
        __syncthreads();
    }
    if (tid < 24) {
        ((float4*)(v_part + (size_t)blockIdx.x * 96))[tid] = sh[0][tid];
    }
}

// ---- K7: reduce v_part -> v[96] (fence-free) ----
__global__ void k_vred(const float* __restrict__ vp, float* __restrict__ v, int nb) {
    int j = blockIdx.x;
    float s = 0.f;
    for (int i = threadIdx.x; i < nb; i += 256) s += vp[(size_t)i * 96 + j];
    __shared__ float sh[256];
    sh[threadIdx.x] = s;
    __syncthreads();
    for (int off = 128; off; off >>= 1) {
        if (threadIdx.x < off) sh[threadIdx.x] += sh[threadIdx.x + off];
        __syncthreads();
    }
    if (threadIdx.x == 0) v[j] = sh[0];
}

// ---- K8: mu = v@W_mu + N*b_mu ; logvar = v@W_lv + N*b_lv ----
__global__ void k_out(const float* __restrict__ v,
                      const float* __restrict__ Wmu, const float* __restrict__ bmu,
                      const float* __restrict__ Wlv, const float* __restrict__ blv,
                      float* __restrict__ out, float nN) {
    int tid = threadIdx.x;
    const float* W = (tid < 64) ? Wmu : Wlv;
    const float* b = (tid < 64) ? bmu : blv;
    int j = tid & 63;
    float s = 0.f;
    #pragma unroll
    for (int k = 0; k < 96; ++k) s = fmaf(v[k], W[k * 64 + j], s);
    out[tid] = s + nN * b[j];
}

extern "C" void kernel_launch(void* const* d_in, const int* in_sizes, int n_in,
                              void* d_out, int out_size, void* d_ws, size_t ws_size,
                              hipStream_t stream) {
    const float* x   = (const float*)d_in[0];
    const int*   ei  = (const int*)d_in[1];
    const float* W1  = (const float*)d_in[2];
    const float* b1  = (const float*)d_in[3];
    const float* Wmu = (const float*)d_in[4];
    const float* bmu = (const float*)d_in[5];
    const float* Wlv = (const float*)d_in[6];
    const float* blv = (const float*)d_in[7];
    float* out = (float*)d_out;

    const int N = in_sizes[0] / 128;   // 50000
    const int E = in_sizes[1] / 2;     // 800000
    const int* src = ei;
    const int* dst = ei + E;

    const int chunkE = (((E + NCHUNK - 1) / NCHUNK) + 3) & ~3;   // 25000
    const int sliceN = (N + NSLICE - 1) / NSLICE;                // 6250
    const int gN = (N + 255) / 256;                              // 196

    size_t off = 0;
    auto alloc = [&](size_t bytes) -> char* {
        off = (off + 255) & ~(size_t)255;
        char* p = (char*)d_ws + off;
        off += bytes;
        return p;
    };
    int*      partial  = (int*)alloc((size_t)NCHUNK * N * 4);  // counts->offs->rsum partials
    int*      rowptr   = (int*)alloc((size_t)(N + 1) * 4);
    int*      col      = (int*)alloc((size_t)E * 4);
    int*      deg      = (int*)alloc((size_t)N * 4);
    float*    dinv     = (float*)alloc((size_t)N * 4);
    float*    cfac     = (float*)alloc((size_t)N * 4);
    int*      blocksum = (int*)alloc((size_t)gN * 4);
    unsigned* g        = (unsigned*)alloc((size_t)N * 96);     // fp8 e4m3, 24 uints/row
    const int nAggBlocks = (N + AGG_NODES - 1) / AGG_NODES;    // 3125
    float*    v_part   = (float*)alloc((size_t)nAggBlocks * 96 * 4);
    float*    v        = (float*)alloc(96 * 4);

    k_count<<<NCHUNK * NSLICE, SORT_T, 0, stream>>>(dst, partial, N, E, chunkE, sliceN);
    k_degdinv<<<gN, 256, 0, stream>>>(partial, deg, dinv, blocksum, N);
    k_offs<<<gN, 256, 0, stream>>>(partial, deg, blocksum, rowptr, N, E, gN);
    k_place<<<NCHUNK * NSLICE, SORT_T, 0, stream>>>(src, dst, dinv, partial, col, N, E, chunkE, sliceN);
    k_gemm<<<(N + 127) / 128, 256, 0, stream>>>(x, W1, dinv, (const float*)partial, cfac, g, N);
    k_agg<<<nAggBlocks, AGG_T, 0, stream>>>(g, col, rowptr, dinv, cfac, b1, v_part, N);
    k_vred<<<96, 256, 0, stream>>>(v_part, v, nAggBlocks);
    k_out<<<1, 128, 0, stream>>>(v, Wmu, bmu, Wlv, blv, out, (float)N);
}

// Round 14
// 92.718 us; speedup vs baseline: 1.2620x; 1.0030x over previous
//
#include <hip/hip_runtime.h>
#include <hip/hip_fp16.h>

// GCN encoder, N=50000, E=800000, 128 -> 96 (relu) -> sum-pooled 64+64.
// Sum-pooled layer 2: out = (sum_u c[u]*h[u]) @ W + N*b,
//   c[u] = dinv[u]*(dinv[u] + rsum[u]),  rsum[u] = sum_{e: src=u} dinv[dst_e].
// Layer 1 with g[u] = (xW1)[u]*dinv[u]  (fp8 e4m3, x16 scale):
//   h[d] = relu( (dinv[d]/16)*(sum_{e->d} g_s[src] + g_s[d]) + b1 )
// 8 kernels: count -> degdinv -> offs -> place -> gemm(+cfac) -> agg -> vred -> out.
// Round-13 change: NSLICE 8->16 (512 sort blocks = 2/CU = full wave capacity;
// count/place were grid-limited to 1 block/CU at 50% waves).
// Lessons pinned (rounds 9-12, all ~+20us each):
//  * NO device-scope spin-wait scans (atomic storm at coherent point).
//  * NO per-block __threadfence/atomic-publish fusions (agent fences force
//    per-XCD L2 writeback on gfx950); kernel-boundary sync is cheaper.
//  * col stays INT; count/place chunk-major (c=bid&31) 1024-thread blocks.

#define NCHUNK 32
#define LOG_NCHUNK 5
#define NSLICE 16
#define SLICE_MAX 3136   // LDS hist capacity; N <= 16*3136
#define SORT_T 1024      // threads for count/place

typedef float v2f __attribute__((ext_vector_type(2)));

__device__ inline void fma4(float4& c, float a, const float4& b) {
    c.x = fmaf(a, b.x, c.x); c.y = fmaf(a, b.y, c.y);
    c.z = fmaf(a, b.z, c.z); c.w = fmaf(a, b.w, c.w);
}

// pack 4 floats -> 4 x fp8 e4m3 in one uint
__device__ inline unsigned pk_fp8(float a, float b, float c, float d) {
    int p = __builtin_amdgcn_cvt_pk_fp8_f32(a, b, 0, false);
    p = __builtin_amdgcn_cvt_pk_fp8_f32(c, d, p, true);
    return (unsigned)p;
}

// ---- K1: per-(chunk,slice) dst histogram via LDS ----
// c = bid & 31 (chunk-major): a chunk's 16 slice-blocks share one XCD's L2.
__launch_bounds__(SORT_T)
__global__ void k_count(const int* __restrict__ dst, int* __restrict__ partial,
                        int N, int E, int chunkE, int sliceN) {
    int c = blockIdx.x & (NCHUNK - 1), s = blockIdx.x >> LOG_NCHUNK;
    int nbase = s * sliceN;
    __shared__ int hist[SLICE_MAX];
    for (int j = threadIdx.x; j < sliceN; j += SORT_T) hist[j] = 0;
    __syncthreads();
    int e0 = c * chunkE, e1 = min(e0 + chunkE, E);
    int ne = e1 - e0;
    const int4* d4 = (const int4*)(dst + e0);
    int n4 = ne >> 2;
    for (int i = threadIdx.x; i < n4; i += SORT_T) {
        int4 d = d4[i];
        unsigned q;
        q = (unsigned)(d.x - nbase); if (q < (unsigned)sliceN) atomicAdd(&hist[q], 1);
        q = (unsigned)(d.y - nbase); if (q < (unsigned)sliceN) atomicAdd(&hist[q], 1);
        q = (unsigned)(d.z - nbase); if (q < (unsigned)sliceN) atomicAdd(&hist[q], 1);
        q = (unsigned)(d.w - nbase); if (q < (unsigned)sliceN) atomicAdd(&hist[q], 1);
    }
    if (threadIdx.x < (ne & 3)) {
        int d = dst[e0 + (n4 << 2) + threadIdx.x];
        unsigned q = (unsigned)(d - nbase);
        if (q < (unsigned)sliceN) atomicAdd(&hist[q], 1);
    }
    __syncthreads();
    for (int j = threadIdx.x; j < sliceN; j += SORT_T) {
        int n = nbase + j;
        if (n < N) partial[(size_t)c * N + n] = hist[j];
    }
}

// ---- K2: deg = sum over chunks; dinv; per-block sum of deg ----
__launch_bounds__(256)
__global__ void k_degdinv(const int* __restrict__ partial, int* __restrict__ deg,
                          float* __restrict__ dinv, int* __restrict__ blocksum, int N) {
    int tid = threadIdx.x;
    int n = blockIdx.x * 256 + tid;
    int s = 0;
    if (n < N) {
        #pragma unroll
        for (int c = 0; c < NCHUNK; ++c) s += partial[(size_t)c * N + n];
        deg[n] = s;
        dinv[n] = rsqrtf((float)(s + 1));
    }
    __shared__ int sh[256];
    sh[tid] = s;
    __syncthreads();
    #pragma unroll
    for (int off = 128; off; off >>= 1) {
        if (tid < off) sh[tid] += sh[tid + off];
        __syncthreads();
    }
    if (tid == 0) blocksum[blockIdx.x] = sh[0];
}

// ---- K3: per-block scan of deg -> rowptr; partial counts -> abs offsets ----
// Block offset = plain reduce of blocksum[b < bid] (nb <= 256), no spinning.
__launch_bounds__(256)
__global__ void k_offs(int* __restrict__ partial, const int* __restrict__ deg,
                       const int* __restrict__ blocksum, int* __restrict__ rowptr,
                       int N, int E, int nb) {
    int tid = threadIdx.x;
    __shared__ int sh[256];
    int bs = (tid < nb && tid < (int)blockIdx.x) ? blocksum[tid] : 0;
    sh[tid] = bs;
    __syncthreads();
    #pragma unroll
    for (int off = 128; off; off >>= 1) {
        if (tid < off) sh[tid] += sh[tid + off];
        __syncthreads();
    }
    int blockoff = sh[0];
    __syncthreads();
    int n = blockIdx.x * 256 + tid;
    int v = (n < N) ? deg[n] : 0;
    sh[tid] = v;
    __syncthreads();
    for (int off = 1; off < 256; off <<= 1) {
        int t = (tid >= off) ? sh[tid - off] : 0;
        __syncthreads();
        sh[tid] += t;
        __syncthreads();
    }
    int run = blockoff + sh[tid] - v;   // exclusive prefix
    if (n < N) {
        rowptr[n] = run;
        #pragma unroll
        for (int c = 0; c < NCHUNK; ++c) {
            size_t ix = (size_t)c * N + n;
            int t = partial[ix];
            partial[ix] = run;
            run += t;
        }
    }
    if (blockIdx.x == 0 && tid == 0) rowptr[N] = E;
}

// ---- K4: place edges into col (int) via LDS cursors; rsum partials into offs ----
__launch_bounds__(SORT_T)
__global__ void k_place(const int* __restrict__ src, const int* __restrict__ dst,
                        const float* __restrict__ dinv, int* __restrict__ offs,
                        int* __restrict__ col, int N, int E, int chunkE, int sliceN) {
    int c = blockIdx.x & (NCHUNK - 1), s = blockIdx.x >> LOG_NCHUNK;
    int nbase = s * sliceN;
    __shared__ int cur[SLICE_MAX];
    __shared__ float rs[SLICE_MAX];
    for (int j = threadIdx.x; j < sliceN; j += SORT_T) {
        int n = nbase + j;
        cur[j] = (n < N) ? offs[(size_t)c * N + n] : 0;
        rs[j] = 0.f;
    }
    __syncthreads();
    int e0 = c * chunkE, e1 = min(e0 + chunkE, E);
    int ne = e1 - e0;
    const int4* s4 = (const int4*)(src + e0);
    const int4* d4 = (const int4*)(dst + e0);
    int n4 = ne >> 2;
    for (int i = threadIdx.x; i < n4; i += SORT_T) {
        int4 sv = s4[i];
        int4 dv = d4[i];
        unsigned qd, qs;
        qd = (unsigned)(dv.x - nbase);
        if (qd < (unsigned)sliceN) { int p = atomicAdd(&cur[qd], 1); col[p] = sv.x; }
        qs = (unsigned)(sv.x - nbase);
        if (qs < (unsigned)sliceN) atomicAdd(&rs[qs], dinv[dv.x]);
        qd = (unsigned)(dv.y - nbase);
        if (qd < (unsigned)sliceN) { int p = atomicAdd(&cur[qd], 1); col[p] = sv.y; }
        qs = (unsigned)(sv.y - nbase);
        if (qs < (unsigned)sliceN) atomicAdd(&rs[qs], dinv[dv.y]);
        qd = (unsigned)(dv.z - nbase);
        if (qd < (unsigned)sliceN) { int p = atomicAdd(&cur[qd], 1); col[p] = sv.z; }
        qs = (unsigned)(sv.z - nbase);
        if (qs < (unsigned)sliceN) atomicAdd(&rs[qs], dinv[dv.z]);
        qd = (unsigned)(dv.w - nbase);
        if (qd < (unsigned)sliceN) { int p = atomicAdd(&cur[qd], 1); col[p] = sv.w; }
        qs = (unsigned)(sv.w - nbase);
        if (qs < (unsigned)sliceN) atomicAdd(&rs[qs], dinv[dv.w]);
    }
    if (threadIdx.x < (ne & 3)) {
        int e = e0 + (n4 << 2) + threadIdx.x;
        int sv = src[e], dv = dst[e];
        unsigned qd = (unsigned)(dv - nbase);
        if (qd < (unsigned)sliceN) { int p = atomicAdd(&cur[qd], 1); col[p] = sv; }
        unsigned qs = (unsigned)(sv - nbase);
        if (qs < (unsigned)sliceN) atomicAdd(&rs[qs], dinv[dv]);
    }
    __syncthreads();
    float* prs = (float*)offs;   // offs[c][this slice] dead after load -> reuse
    for (int j = threadIdx.x; j < sliceN; j += SORT_T) {
        int n = nbase + j;
        if (n < N) prs[(size_t)c * N + n] = rs[j];
    }
}

// ---- K5: g = fp8(16*(x @ W1)*dinv[row]); fused cfac = dinv*(dinv+rsum) ----
__launch_bounds__(256)
__global__ void k_gemm(const float* __restrict__ x, const float* __restrict__ W1,
                       const float* __restrict__ dinv, const float* __restrict__ prs,
                       float* __restrict__ cfac, unsigned* __restrict__ g, int n) {
    __shared__ float Ws[128 * 96];
    int tid = threadIdx.x;
    {
        const float4* wsrc = (const float4*)W1;
        float4* wdst = (float4*)Ws;
        #pragma unroll
        for (int i = 0; i < 12; ++i) wdst[tid + 256 * i] = wsrc[tid + 256 * i];
    }
    // fused rsum->cfac for this block's 128 rows (overlaps staging)
    {
        int r = blockIdx.x * 128 + tid;
        if (tid < 128 && r < n) {
            float s = 0.f;
            #pragma unroll
            for (int c = 0; c < NCHUNK; ++c) s += prs[(size_t)c * n + r];
            float dv = dinv[r];
            cfac[r] = dv * (dv + s);
        }
    }
    __syncthreads();

    int tx = tid & 7;          // 8 col groups of 12
    int ty = tid >> 3;         // 32 row quads
    int rbase = blockIdx.x * 128 + ty * 4;
    const float4* xp[4];
    bool vr[4];
    #pragma unroll
    for (int i = 0; i < 4; ++i) {
        int r = rbase + i;
        vr[i] = r < n;
        xp[i] = (const float4*)(x + (size_t)(vr[i] ? r : 0) * 128);
    }

    float4 acc[4][3];
    #pragma unroll
    for (int i = 0; i < 4; ++i)
        #pragma unroll
        for (int j = 0; j < 3; ++j) acc[i][j] = make_float4(0.f, 0.f, 0.f, 0.f);

    #pragma unroll 2
    for (int k4 = 0; k4 < 32; ++k4) {
        float4 a0 = xp[0][k4];
        float4 a1 = xp[1][k4];
        float4 a2 = xp[2][k4];
        float4 a3 = xp[3][k4];
        #pragma unroll
        for (int kk = 0; kk < 4; ++kk) {
            const float* wrow = &Ws[(k4 * 4 + kk) * 96 + tx * 12];
            float4 b0 = *(const float4*)(wrow);
            float4 b1 = *(const float4*)(wrow + 4);
            float4 b2 = *(const float4*)(wrow + 8);
            float av0 = (kk == 0) ? a0.x : (kk == 1) ? a0.y : (kk == 2) ? a0.z : a0.w;
            float av1 = (kk == 0) ? a1.x : (kk == 1) ? a1.y : (kk == 2) ? a1.z : a1.w;
            float av2 = (kk == 0) ? a2.x : (kk == 1) ? a2.y : (kk == 2) ? a2.z : a2.w;
            float av3 = (kk == 0) ? a3.x : (kk == 1) ? a3.y : (kk == 2) ? a3.z : a3.w;
            fma4(acc[0][0], av0, b0); fma4(acc[0][1], av0, b1); fma4(acc[0][2], av0, b2);
            fma4(acc[1][0], av1, b0); fma4(acc[1][1], av1, b1); fma4(acc[1][2], av1, b2);
            fma4(acc[2][0], av2, b0); fma4(acc[2][1], av2, b1); fma4(acc[2][2], av2, b2);
            fma4(acc[3][0], av3, b0); fma4(acc[3][1], av3, b1); fma4(acc[3][2], av3, b2);
        }
    }

    #pragma unroll
    for (int i = 0; i < 4; ++i) {
        if (!vr[i]) continue;
        int r = rbase + i;
        float dv = dinv[r] * 16.f;      // x16 scale for fp8 dynamic range
        unsigned* o = g + (size_t)r * 24 + tx * 3;
        float4 t;
        t = acc[i][0]; o[0] = pk_fp8(t.x * dv, t.y * dv, t.z * dv, t.w * dv);
        t = acc[i][1]; o[1] = pk_fp8(t.x * dv, t.y * dv, t.z * dv, t.w * dv);
        t = acc[i][2]; o[2] = pk_fp8(t.x * dv, t.y * dv, t.z * dv, t.w * dv);
    }
}

// ---- K6: per-node fp8 gather + fused bias/relu/cfac + block partial of v ----
#define AGG_NODES 16
#define AGG_T (AGG_NODES * 24)
__launch_bounds__(AGG_T)
__global__ void k_agg(const unsigned* __restrict__ g1, const int* __restrict__ col,
                      const int* __restrict__ rowptr, const float* __restrict__ dinv,
                      const float* __restrict__ cfac, const float* __restrict__ b1,
                      float* __restrict__ v_part, int n) {
    int tid = threadIdx.x;
    int nl = tid / 24;
    int ch = tid % 24;        // uint chunk of the 24-uint row (4 fp8 each)
    int d = blockIdx.x * AGG_NODES + nl;

    __shared__ float4 sh[AGG_NODES][24];

    float4 contrib = make_float4(0.f, 0.f, 0.f, 0.f);
    if (d < n) {
        float dds = dinv[d] * 0.0625f;   // undo x16 storage scale
        int e0 = rowptr[d], e1 = rowptr[d + 1];
        float4 aA = make_float4(0.f, 0.f, 0.f, 0.f);
        float4 aB = make_float4(0.f, 0.f, 0.f, 0.f);
        int e = e0;
        for (; e + 4 <= e1; e += 4) {
            int s0 = col[e], s1 = col[e + 1], s2 = col[e + 2], s3 = col[e + 3];
            unsigned u0 = g1[(size_t)s0 * 24 + ch];
            unsigned u1 = g1[(size_t)s1 * 24 + ch];
            unsigned u2 = g1[(size_t)s2 * 24 + ch];
            unsigned u3 = g1[(size_t)s3 * 24 + ch];
            v2f f;
            f = __builtin_amdgcn_cvt_pk_f32_fp8(u0, false); aA.x += f.x; aA.y += f.y;
            f = __builtin_amdgcn_cvt_pk_f32_fp8(u0, true);  aA.z += f.x; aA.w += f.y;
            f = __builtin_amdgcn_cvt_pk_f32_fp8(u1, false); aB.x += f.x; aB.y += f.y;
            f = __builtin_amdgcn_cvt_pk_f32_fp8(u1, true);  aB.z += f.x; aB.w += f.y;
            f = __builtin_amdgcn_cvt_pk_f32_fp8(u2, false); aA.x += f.x; aA.y += f.y;
            f = __builtin_amdgcn_cvt_pk_f32_fp8(u2, true);  aA.z += f.x; aA.w += f.y;
            f = __builtin_amdgcn_cvt_pk_f32_fp8(u3, false); aB.x += f.x; aB.y += f.y;
            f = __builtin_amdgcn_cvt_pk_f32_fp8(u3, true);  aB.z += f.x; aB.w += f.y;
        }
        for (; e < e1; ++e) {
            unsigned u = g1[(size_t)col[e] * 24 + ch];
            v2f f;
            f = __builtin_amdgcn_cvt_pk_f32_fp8(u, false); aA.x += f.x; aA.y += f.y;
            f = __builtin_amdgcn_cvt_pk_f32_fp8(u, true);  aA.z += f.x; aA.w += f.y;
        }
        {   // analytic self-loop: g[d] joins the same sum
            unsigned u = g1[(size_t)d * 24 + ch];
            v2f f;
            f = __builtin_amdgcn_cvt_pk_f32_fp8(u, false); aA.x += f.x; aA.y += f.y;
            f = __builtin_amdgcn_cvt_pk_f32_fp8(u, true);  aA.z += f.x; aA.w += f.y;
        }
        float4 b1c = ((const float4*)b1)[ch];
        float cd = cfac[d];
        float hx = fmaxf(fmaf(dds, aA.x + aB.x, b1c.x), 0.f);
        float hy = fmaxf(fmaf(dds, aA.y + aB.y, b1c.y), 0.f);
        float hz = fmaxf(fmaf(dds, aA.z + aB.z, b1c.z), 0.f);
        float hw = fmaxf(fmaf(dds, aA.w + aB.w, b1c.w), 0.f);
        contrib = make_float4(cd * hx, cd * hy, cd * hz, cd * hw);
    }
    sh[nl][ch] = contrib;
    __syncthreads();
    #pragma unroll
    for (int off = 8; off >= 1; off >>= 1) {
        if (nl < off) {
            float4 a = sh[nl][ch];
            float4 b = sh[nl + off][ch];
            a.x += b.x; a.y += b.y; a.z += b.z; a.w += b.w;
            sh[nl][ch] = a;
        }
        __syncthreads();
    }
    if (tid < 24) {
        ((float4*)(v_part + (size_t)blockIdx.x * 96))[tid] = sh[0][tid];
    }
}

// ---- K7: reduce v_part -> v[96] (fence-free) ----
__global__ void k_vred(const float* __restrict__ vp, float* __restrict__ v, int nb) {
    int j = blockIdx.x;
    float s = 0.f;
    for (int i = threadIdx.x; i < nb; i += 256) s += vp[(size_t)i * 96 + j];
    __shared__ float sh[256];
    sh[threadIdx.x] = s;
    __syncthreads();
    for (int off = 128; off; off >>= 1) {
        if (threadIdx.x < off) sh[threadIdx.x] += sh[threadIdx.x + off];
        __syncthreads();
    }
    if (threadIdx.x == 0) v[j] = sh[0];
}

// ---- K8: mu = v@W_mu + N*b_mu ; logvar = v@W_lv + N*b_lv ----
__global__ void k_out(const float* __restrict__ v,
                      const float* __restrict__ Wmu, const float* __restrict__ bmu,
                      const float* __restrict__ Wlv, const float* __restrict__ blv,
                      float* __restrict__ out, float nN) {
    int tid = threadIdx.x;
    const float* W = (tid < 64) ? Wmu : Wlv;
    const float* b = (tid < 64) ? bmu : blv;
    int j = tid & 63;
    float s = 0.f;
    #pragma unroll
    for (int k = 0; k < 96; ++k) s = fmaf(v[k], W[k * 64 + j], s);
    out[tid] = s + nN * b[j];
}

extern "C" void kernel_launch(void* const* d_in, const int* in_sizes, int n_in,
                              void* d_out, int out_size, void* d_ws, size_t ws_size,
                              hipStream_t stream) {
    const float* x   = (const float*)d_in[0];
    const int*   ei  = (const int*)d_in[1];
    const float* W1  = (const float*)d_in[2];
    const float* b1  = (const float*)d_in[3];
    const float* Wmu = (const float*)d_in[4];
    const float* bmu = (const float*)d_in[5];
    const float* Wlv = (const float*)d_in[6];
    const float* blv = (const float*)d_in[7];
    float* out = (float*)d_out;

    const int N = in_sizes[0] / 128;   // 50000
    const int E = in_sizes[1] / 2;     // 800000
    const int* src = ei;
    const int* dst = ei + E;

    const int chunkE = (((E + NCHUNK - 1) / NCHUNK) + 3) & ~3;   // 25000
    const int sliceN = (N + NSLICE - 1) / NSLICE;                // 3125
    const int gN = (N + 255) / 256;                              // 196

    size_t off = 0;
    auto alloc = [&](size_t bytes) -> char* {
        off = (off + 255) & ~(size_t)255;
        char* p = (char*)d_ws + off;
        off += bytes;
        return p;
    };
    int*      partial  = (int*)alloc((size_t)NCHUNK * N * 4);  // counts->offs->rsum partials
    int*      rowptr   = (int*)alloc((size_t)(N + 1) * 4);
    int*      col      = (int*)alloc((size_t)E * 4);
    int*      deg      = (int*)alloc((size_t)N * 4);
    float*    dinv     = (float*)alloc((size_t)N * 4);
    float*    cfac     = (float*)alloc((size_t)N * 4);
    int*      blocksum = (int*)alloc((size_t)gN * 4);
    unsigned* g        = (unsigned*)alloc((size_t)N * 96);     // fp8 e4m3, 24 uints/row
    const int nAggBlocks = (N + AGG_NODES - 1) / AGG_NODES;    // 3125
    float*    v_part   = (float*)alloc((size_t)nAggBlocks * 96 * 4);
    float*    v        = (float*)alloc(96 * 4);

    k_count<<<NCHUNK * NSLICE, SORT_T, 0, stream>>>(dst, partial, N, E, chunkE, sliceN);
    k_degdinv<<<gN, 256, 0, stream>>>(partial, deg, dinv, blocksum, N);
    k_offs<<<gN, 256, 0, stream>>>(partial, deg, blocksum, rowptr, N, E, gN);
    k_place<<<NCHUNK * NSLICE, SORT_T, 0, stream>>>(src, dst, dinv, partial, col, N, E, chunkE, sliceN);
    k_gemm<<<(N + 127) / 128, 256, 0, stream>>>(x, W1, dinv, (const float*)partial, cfac, g, N);
    k_agg<<<nAggBlocks, AGG_T, 0, stream>>>(g, col, rowptr, dinv, cfac, b1, v_part, N);
    k_vred<<<96, 256, 0, stream>>>(v_part, v, nAggBlocks);
    k_out<<<1, 128, 0, stream>>>(v, Wmu, bmu, Wlv, blv, out, (float)N);
}

// Round 15
// 92.198 us; speedup vs baseline: 1.2691x; 1.0056x over previous
//
#include <hip/hip_runtime.h>
#include <hip/hip_fp16.h>

// GCN encoder, N=50000, E=800000, 128 -> 96 (relu) -> sum-pooled 64+64.
// Sum-pooled layer 2: out = (sum_u c[u]*h[u]) @ W + N*b,
//   c[u] = dinv[u]*(dinv[u] + rsum[u]),  rsum[u] = sum_{e: src=u} dinv[dst_e].
// Layer 1 with g[u] = (xW1)[u]*dinv[u]  (fp8 e4m3, x16 scale):
//   h[d] = relu( (dinv[d]/16)*(sum_{e->d} g_s[src] + g_s[d]) + b1 )
// 8 kernels: count -> degdinv -> offs -> place -> gemm(+cfac) -> agg -> vred -> out.
// Round-14 changes: (1) k_agg unroll-8, 4 accumulators, nontemporal col loads
// (protect g's L2 residency); (2) counts stored as ushort (pcount), offsets
// written to separate int buffer (less RMW traffic).
// Lessons pinned (rounds 9-13):
//  * NO device-scope spin-wait scans (atomic storm at coherent point, +20us).
//  * NO per-block __threadfence/atomic-publish fusions (+20us; agent fences
//    force per-XCD L2 writeback on gfx950). Kernel-boundary sync is cheaper.
//  * col stays INT; count/place chunk-major (c=bid&31) 1024-thread blocks.
//  * NSLICE 8 vs 16: null (not wave-limited). Keep 16.

#define NCHUNK 32
#define LOG_NCHUNK 5
#define NSLICE 16
#define SLICE_MAX 3136   // LDS hist capacity; N <= 16*3136
#define SORT_T 1024      // threads for count/place

typedef float v2f __attribute__((ext_vector_type(2)));

__device__ inline void fma4(float4& c, float a, const float4& b) {
    c.x = fmaf(a, b.x, c.x); c.y = fmaf(a, b.y, c.y);
    c.z = fmaf(a, b.z, c.z); c.w = fmaf(a, b.w, c.w);
}

// pack 4 floats -> 4 x fp8 e4m3 in one uint
__device__ inline unsigned pk_fp8(float a, float b, float c, float d) {
    int p = __builtin_amdgcn_cvt_pk_fp8_f32(a, b, 0, false);
    p = __builtin_amdgcn_cvt_pk_fp8_f32(c, d, p, true);
    return (unsigned)p;
}

__device__ inline void add_fp8(float4& acc, unsigned u) {
    v2f f;
    f = __builtin_amdgcn_cvt_pk_f32_fp8(u, false); acc.x += f.x; acc.y += f.y;
    f = __builtin_amdgcn_cvt_pk_f32_fp8(u, true);  acc.z += f.x; acc.w += f.y;
}

// ---- K1: per-(chunk,slice) dst histogram via LDS -> ushort pcount ----
// c = bid & 31 (chunk-major): a chunk's slice-blocks share one XCD's L2.
__launch_bounds__(SORT_T)
__global__ void k_count(const int* __restrict__ dst, unsigned short* __restrict__ pcount,
                        int N, int E, int chunkE, int sliceN) {
    int c = blockIdx.x & (NCHUNK - 1), s = blockIdx.x >> LOG_NCHUNK;
    int nbase = s * sliceN;
    __shared__ int hist[SLICE_MAX];
    for (int j = threadIdx.x; j < sliceN; j += SORT_T) hist[j] = 0;
    __syncthreads();
    int e0 = c * chunkE, e1 = min(e0 + chunkE, E);
    int ne = e1 - e0;
    const int4* d4 = (const int4*)(dst + e0);
    int n4 = ne >> 2;
    for (int i = threadIdx.x; i < n4; i += SORT_T) {
        int4 d = d4[i];
        unsigned q;
        q = (unsigned)(d.x - nbase); if (q < (unsigned)sliceN) atomicAdd(&hist[q], 1);
        q = (unsigned)(d.y - nbase); if (q < (unsigned)sliceN) atomicAdd(&hist[q], 1);
        q = (unsigned)(d.z - nbase); if (q < (unsigned)sliceN) atomicAdd(&hist[q], 1);
        q = (unsigned)(d.w - nbase); if (q < (unsigned)sliceN) atomicAdd(&hist[q], 1);
    }
    if (threadIdx.x < (ne & 3)) {
        int d = dst[e0 + (n4 << 2) + threadIdx.x];
        unsigned q = (unsigned)(d - nbase);
        if (q < (unsigned)sliceN) atomicAdd(&hist[q], 1);
    }
    __syncthreads();
    for (int j = threadIdx.x; j < sliceN; j += SORT_T) {
        int n = nbase + j;
        if (n < N) pcount[(size_t)c * N + n] = (unsigned short)hist[j];
    }
}

// ---- K2: deg = sum over chunks (ushort); dinv; per-block sum of deg ----
__launch_bounds__(256)
__global__ void k_degdinv(const unsigned short* __restrict__ pcount, int* __restrict__ deg,
                          float* __restrict__ dinv, int* __restrict__ blocksum, int N) {
    int tid = threadIdx.x;
    int n = blockIdx.x * 256 + tid;
    int s = 0;
    if (n < N) {
        #pragma unroll
        for (int c = 0; c < NCHUNK; ++c) s += pcount[(size_t)c * N + n];
        deg[n] = s;
        dinv[n] = rsqrtf((float)(s + 1));
    }
    __shared__ int sh[256];
    sh[tid] = s;
    __syncthreads();
    #pragma unroll
    for (int off = 128; off; off >>= 1) {
        if (tid < off) sh[tid] += sh[tid + off];
        __syncthreads();
    }
    if (tid == 0) blocksum[blockIdx.x] = sh[0];
}

// ---- K3: per-block scan of deg -> rowptr; pcount -> abs offsets (int) ----
// Block offset = plain reduce of blocksum[b < bid] (nb <= 256), no spinning.
__launch_bounds__(256)
__global__ void k_offs(const unsigned short* __restrict__ pcount, int* __restrict__ offs,
                       const int* __restrict__ deg, const int* __restrict__ blocksum,
                       int* __restrict__ rowptr, int N, int E, int nb) {
    int tid = threadIdx.x;
    __shared__ int sh[256];
    int bs = (tid < nb && tid < (int)blockIdx.x) ? blocksum[tid] : 0;
    sh[tid] = bs;
    __syncthreads();
    #pragma unroll
    for (int off = 128; off; off >>= 1) {
        if (tid < off) sh[tid] += sh[tid + off];
        __syncthreads();
    }
    int blockoff = sh[0];
    __syncthreads();
    int n = blockIdx.x * 256 + tid;
    int v = (n < N) ? deg[n] : 0;
    sh[tid] = v;
    __syncthreads();
    for (int off = 1; off < 256; off <<= 1) {
        int t = (tid >= off) ? sh[tid - off] : 0;
        __syncthreads();
        sh[tid] += t;
        __syncthreads();
    }
    int run = blockoff + sh[tid] - v;   // exclusive prefix
    if (n < N) {
        rowptr[n] = run;
        #pragma unroll
        for (int c = 0; c < NCHUNK; ++c) {
            size_t ix = (size_t)c * N + n;
            int t = pcount[ix];
            offs[ix] = run;
            run += t;
        }
    }
    if (blockIdx.x == 0 && tid == 0) rowptr[N] = E;
}

// ---- K4: place edges into col (int) via LDS cursors; rsum partials into offs ----
__launch_bounds__(SORT_T)
__global__ void k_place(const int* __restrict__ src, const int* __restrict__ dst,
                        const float* __restrict__ dinv, int* __restrict__ offs,
                        int* __restrict__ col, int N, int E, int chunkE, int sliceN) {
    int c = blockIdx.x & (NCHUNK - 1), s = blockIdx.x >> LOG_NCHUNK;
    int nbase = s * sliceN;
    __shared__ int cur[SLICE_MAX];
    __shared__ float rs[SLICE_MAX];
    for (int j = threadIdx.x; j < sliceN; j += SORT_T) {
        int n = nbase + j;
        cur[j] = (n < N) ? offs[(size_t)c * N + n] : 0;
        rs[j] = 0.f;
    }
    __syncthreads();
    int e0 = c * chunkE, e1 = min(e0 + chunkE, E);
    int ne = e1 - e0;
    const int4* s4 = (const int4*)(src + e0);
    const int4* d4 = (const int4*)(dst + e0);
    int n4 = ne >> 2;
    for (int i = threadIdx.x; i < n4; i += SORT_T) {
        int4 sv = s4[i];
        int4 dv = d4[i];
        unsigned qd, qs;
        qd = (unsigned)(dv.x - nbase);
        if (qd < (unsigned)sliceN) { int p = atomicAdd(&cur[qd], 1); col[p] = sv.x; }
        qs = (unsigned)(sv.x - nbase);
        if (qs < (unsigned)sliceN) atomicAdd(&rs[qs], dinv[dv.x]);
        qd = (unsigned)(dv.y - nbase);
        if (qd < (unsigned)sliceN) { int p = atomicAdd(&cur[qd], 1); col[p] = sv.y; }
        qs = (unsigned)(sv.y - nbase);
        if (qs < (unsigned)sliceN) atomicAdd(&rs[qs], dinv[dv.y]);
        qd = (unsigned)(dv.z - nbase);
        if (qd < (unsigned)sliceN) { int p = atomicAdd(&cur[qd], 1); col[p] = sv.z; }
        qs = (unsigned)(sv.z - nbase);
        if (qs < (unsigned)sliceN) atomicAdd(&rs[qs], dinv[dv.z]);
        qd = (unsigned)(dv.w - nbase);
        if (qd < (unsigned)sliceN) { int p = atomicAdd(&cur[qd], 1); col[p] = sv.w; }
        qs = (unsigned)(sv.w - nbase);
        if (qs < (unsigned)sliceN) atomicAdd(&rs[qs], dinv[dv.w]);
    }
    if (threadIdx.x < (ne & 3)) {
        int e = e0 + (n4 << 2) + threadIdx.x;
        int sv = src[e], dv = dst[e];
        unsigned qd = (unsigned)(dv - nbase);
        if (qd < (unsigned)sliceN) { int p = atomicAdd(&cur[qd], 1); col[p] = sv; }
        unsigned qs = (unsigned)(sv - nbase);
        if (qs < (unsigned)sliceN) atomicAdd(&rs[qs], dinv[dv]);
    }
    __syncthreads();
    float* prs = (float*)offs;   // offs[c][this slice] dead after load -> reuse
    for (int j = threadIdx.x; j < sliceN; j += SORT_T) {
        int n = nbase + j;
        if (n < N) prs[(size_t)c * N + n] = rs[j];
    }
}

// ---- K5: g = fp8(16*(x @ W1)*dinv[row]); fused cfac = dinv*(dinv+rsum) ----
__launch_bounds__(256)
__global__ void k_gemm(const float* __restrict__ x, const float* __restrict__ W1,
                       const float* __restrict__ dinv, const float* __restrict__ prs,
                       float* __restrict__ cfac, unsigned* __restrict__ g, int n) {
    __shared__ float Ws[128 * 96];
    int tid = threadIdx.x;
    {
        const float4* wsrc = (const float4*)W1;
        float4* wdst = (float4*)Ws;
        #pragma unroll
        for (int i = 0; i < 12; ++i) wdst[tid + 256 * i] = wsrc[tid + 256 * i];
    }
    // fused rsum->cfac for this block's 128 rows (overlaps staging)
    {
        int r = blockIdx.x * 128 + tid;
        if (tid < 128 && r < n) {
            float s = 0.f;
            #pragma unroll
            for (int c = 0; c < NCHUNK; ++c) s += prs[(size_t)c * n + r];
            float dv = dinv[r];
            cfac[r] = dv * (dv + s);
        }
    }
    __syncthreads();

    int tx = tid & 7;          // 8 col groups of 12
    int ty = tid >> 3;         // 32 row quads
    int rbase = blockIdx.x * 128 + ty * 4;
    const float4* xp[4];
    bool vr[4];
    #pragma unroll
    for (int i = 0; i < 4; ++i) {
        int r = rbase + i;
        vr[i] = r < n;
        xp[i] = (const float4*)(x + (size_t)(vr[i] ? r : 0) * 128);
    }

    float4 acc[4][3];
    #pragma unroll
    for (int i = 0; i < 4; ++i)
        #pragma unroll
        for (int j = 0; j < 3; ++j) acc[i][j] = make_float4(0.f, 0.f, 0.f, 0.f);

    #pragma unroll 2
    for (int k4 = 0; k4 < 32; ++k4) {
        float4 a0 = xp[0][k4];
        float4 a1 = xp[1][k4];
        float4 a2 = xp[2][k4];
        float4 a3 = xp[3][k4];
        #pragma unroll
        for (int kk = 0; kk < 4; ++kk) {
            const float* wrow = &Ws[(k4 * 4 + kk) * 96 + tx * 12];
            float4 b0 = *(const float4*)(wrow);
            float4 b1 = *(const float4*)(wrow + 4);
            float4 b2 = *(const float4*)(wrow + 8);
            float av0 = (kk == 0) ? a0.x : (kk == 1) ? a0.y : (kk == 2) ? a0.z : a0.w;
            float av1 = (kk == 0) ? a1.x : (kk == 1) ? a1.y : (kk == 2) ? a1.z : a1.w;
            float av2 = (kk == 0) ? a2.x : (kk == 1) ? a2.y : (kk == 2) ? a2.z : a2.w;
            float av3 = (kk == 0) ? a3.x : (kk == 1) ? a3.y : (kk == 2) ? a3.z : a3.w;
            fma4(acc[0][0], av0, b0); fma4(acc[0][1], av0, b1); fma4(acc[0][2], av0, b2);
            fma4(acc[1][0], av1, b0); fma4(acc[1][1], av1, b1); fma4(acc[1][2], av1, b2);
            fma4(acc[2][0], av2, b0); fma4(acc[2][1], av2, b1); fma4(acc[2][2], av2, b2);
            fma4(acc[3][0], av3, b0); fma4(acc[3][1], av3, b1); fma4(acc[3][2], av3, b2);
        }
    }

    #pragma unroll
    for (int i = 0; i < 4; ++i) {
        if (!vr[i]) continue;
        int r = rbase + i;
        float dv = dinv[r] * 16.f;      // x16 scale for fp8 dynamic range
        unsigned* o = g + (size_t)r * 24 + tx * 3;
        float4 t;
        t = acc[i][0]; o[0] = pk_fp8(t.x * dv, t.y * dv, t.z * dv, t.w * dv);
        t = acc[i][1]; o[1] = pk_fp8(t.x * dv, t.y * dv, t.z * dv, t.w * dv);
        t = acc[i][2]; o[2] = pk_fp8(t.x * dv, t.y * dv, t.z * dv, t.w * dv);
    }
}

// ---- K6: per-node fp8 gather (unroll-8, 4 accumulators, NT col loads) ----
#define AGG_NODES 16
#define AGG_T (AGG_NODES * 24)
__launch_bounds__(AGG_T)
__global__ void k_agg(const unsigned* __restrict__ g1, const int* __restrict__ col,
                      const int* __restrict__ rowptr, const float* __restrict__ dinv,
                      const float* __restrict__ cfac, const float* __restrict__ b1,
                      float* __restrict__ v_part, int n) {
    int tid = threadIdx.x;
    int nl = tid / 24;
    int ch = tid % 24;        // uint chunk of the 24-uint row (4 fp8 each)
    int d = blockIdx.x * AGG_NODES + nl;

    __shared__ float4 sh[AGG_NODES][24];

    float4 contrib = make_float4(0.f, 0.f, 0.f, 0.f);
    if (d < n) {
        float dds = dinv[d] * 0.0625f;   // undo x16 storage scale
        int e0 = rowptr[d], e1 = rowptr[d + 1];
        float4 aA = make_float4(0.f, 0.f, 0.f, 0.f);
        float4 aB = make_float4(0.f, 0.f, 0.f, 0.f);
        float4 aC = make_float4(0.f, 0.f, 0.f, 0.f);
        float4 aD = make_float4(0.f, 0.f, 0.f, 0.f);
        int e = e0;
        for (; e + 8 <= e1; e += 8) {
            int s0 = __builtin_nontemporal_load(col + e);
            int s1 = __builtin_nontemporal_load(col + e + 1);
            int s2 = __builtin_nontemporal_load(col + e + 2);
            int s3 = __builtin_nontemporal_load(col + e + 3);
            int s4 = __builtin_nontemporal_load(col + e + 4);
            int s5 = __builtin_nontemporal_load(col + e + 5);
            int s6 = __builtin_nontemporal_load(col + e + 6);
            int s7 = __builtin_nontemporal_load(col + e + 7);
            unsigned u0 = g1[(size_t)s0 * 24 + ch];
            unsigned u1 = g1[(size_t)s1 * 24 + ch];
            unsigned u2 = g1[(size_t)s2 * 24 + ch];
            unsigned u3 = g1[(size_t)s3 * 24 + ch];
            unsigned u4 = g1[(size_t)s4 * 24 + ch];
            unsigned u5 = g1[(size_t)s5 * 24 + ch];
            unsigned u6 = g1[(size_t)s6 * 24 + ch];
            unsigned u7 = g1[(size_t)s7 * 24 + ch];
            add_fp8(aA, u0); add_fp8(aB, u1); add_fp8(aC, u2); add_fp8(aD, u3);
            add_fp8(aA, u4); add_fp8(aB, u5); add_fp8(aC, u6); add_fp8(aD, u7);
        }
        for (; e + 2 <= e1; e += 2) {
            int s0 = __builtin_nontemporal_load(col + e);
            int s1 = __builtin_nontemporal_load(col + e + 1);
            unsigned u0 = g1[(size_t)s0 * 24 + ch];
            unsigned u1 = g1[(size_t)s1 * 24 + ch];
            add_fp8(aA, u0); add_fp8(aB, u1);
        }
        if (e < e1) {
            int s0 = __builtin_nontemporal_load(col + e);
            add_fp8(aC, g1[(size_t)s0 * 24 + ch]);
        }
        add_fp8(aD, g1[(size_t)d * 24 + ch]);   // analytic self-loop
        float4 b1c = ((const float4*)b1)[ch];
        float cd = cfac[d];
        float hx = fmaxf(fmaf(dds, (aA.x + aB.x) + (aC.x + aD.x), b1c.x), 0.f);
        float hy = fmaxf(fmaf(dds, (aA.y + aB.y) + (aC.y + aD.y), b1c.y), 0.f);
        float hz = fmaxf(fmaf(dds, (aA.z + aB.z) + (aC.z + aD.z), b1c.z), 0.f);
        float hw = fmaxf(fmaf(dds, (aA.w + aB.w) + (aC.w + aD.w), b1c.w), 0.f);
        contrib = make_float4(cd * hx, cd * hy, cd * hz, cd * hw);
    }
    sh[nl][ch] = contrib;
    __syncthreads();
    #pragma unroll
    for (int off = 8; off >= 1; off >>= 1) {
        if (nl < off) {
            float4 a = sh[nl][ch];
            float4 b = sh[nl + off][ch];
            a.x += b.x; a.y += b.y; a.z += b.z; a.w += b.w;
            sh[nl][ch] = a;
        }
        __syncthreads();
    }
    if (tid < 24) {
        ((float4*)(v_part + (size_t)blockIdx.x * 96))[tid] = sh[0][tid];
    }
}

// ---- K7: reduce v_part -> v[96] (fence-free) ----
__global__ void k_vred(const float* __restrict__ vp, float* __restrict__ v, int nb) {
    int j = blockIdx.x;
    float s = 0.f;
    for (int i = threadIdx.x; i < nb; i += 256) s += vp[(size_t)i * 96 + j];
    __shared__ float sh[256];
    sh[threadIdx.x] = s;
    __syncthreads();
    for (int off = 128; off; off >>= 1) {
        if (threadIdx.x < off) sh[threadIdx.x] += sh[threadIdx.x + off];
        __syncthreads();
    }
    if (threadIdx.x == 0) v[j] = sh[0];
}

// ---- K8: mu = v@W_mu + N*b_mu ; logvar = v@W_lv + N*b_lv ----
__global__ void k_out(const float* __restrict__ v,
                      const float* __restrict__ Wmu, const float* __restrict__ bmu,
                      const float* __restrict__ Wlv, const float* __restrict__ blv,
                      float* __restrict__ out, float nN) {
    int tid = threadIdx.x;
    const float* W = (tid < 64) ? Wmu : Wlv;
    const float* b = (tid < 64) ? bmu : blv;
    int j = tid & 63;
    float s = 0.f;
    #pragma unroll
    for (int k = 0; k < 96; ++k) s = fmaf(v[k], W[k * 64 + j], s);
    out[tid] = s + nN * b[j];
}

extern "C" void kernel_launch(void* const* d_in, const int* in_sizes, int n_in,
                              void* d_out, int out_size, void* d_ws, size_t ws_size,
                              hipStream_t stream) {
    const float* x   = (const float*)d_in[0];
    const int*   ei  = (const int*)d_in[1];
    const float* W1  = (const float*)d_in[2];
    const float* b1  = (const float*)d_in[3];
    const float* Wmu = (const float*)d_in[4];
    const float* bmu = (const float*)d_in[5];
    const float* Wlv = (const float*)d_in[6];
    const float* blv = (const float*)d_in[7];
    float* out = (float*)d_out;

    const int N = in_sizes[0] / 128;   // 50000
    const int E = in_sizes[1] / 2;     // 800000
    const int* src = ei;
    const int* dst = ei + E;

    const int chunkE = (((E + NCHUNK - 1) / NCHUNK) + 3) & ~3;   // 25000
    const int sliceN = (N + NSLICE - 1) / NSLICE;                // 3125
    const int gN = (N + 255) / 256;                              // 196

    size_t off = 0;
    auto alloc = [&](size_t bytes) -> char* {
        off = (off + 255) & ~(size_t)255;
        char* p = (char*)d_ws + off;
        off += bytes;
        return p;
    };
    unsigned short* pcount = (unsigned short*)alloc((size_t)NCHUNK * N * 2);  // counts
    int*      offsb    = (int*)alloc((size_t)NCHUNK * N * 4);  // offsets -> rsum partials
    int*      rowptr   = (int*)alloc((size_t)(N + 1) * 4);
    int*      col      = (int*)alloc((size_t)E * 4);
    int*      deg      = (int*)alloc((size_t)N * 4);
    float*    dinv     = (float*)alloc((size_t)N * 4);
    float*    cfac     = (float*)alloc((size_t)N * 4);
    int*      blocksum = (int*)alloc((size_t)gN * 4);
    unsigned* g        = (unsigned*)alloc((size_t)N * 96);     // fp8 e4m3, 24 uints/row
    const int nAggBlocks = (N + AGG_NODES - 1) / AGG_NODES;    // 3125
    float*    v_part   = (float*)alloc((size_t)nAggBlocks * 96 * 4);
    float*    v        = (float*)alloc(96 * 4);

    k_count<<<NCHUNK * NSLICE, SORT_T, 0, stream>>>(dst, pcount, N, E, chunkE, sliceN);
    k_degdinv<<<gN, 256, 0, stream>>>(pcount, deg, dinv, blocksum, N);
    k_offs<<<gN, 256, 0, stream>>>(pcount, offsb, deg, blocksum, rowptr, N, E, gN);
    k_place<<<NCHUNK * NSLICE, SORT_T, 0, stream>>>(src, dst, dinv, offsb, col, N, E, chunkE, sliceN);
    k_gemm<<<(N + 127) / 128, 256, 0, stream>>>(x, W1, dinv, (const float*)offsb, cfac, g, N);
    k_agg<<<nAggBlocks, AGG_T, 0, stream>>>(g, col, rowptr, dinv, cfac, b1, v_part, N);
    k_vred<<<96, 256, 0, stream>>>(v_part, v, nAggBlocks);
    k_out<<<1, 128, 0, stream>>>(v, Wmu, bmu, Wlv, blv, out, (float)N);
}

// Round 16
// 83.453 us; speedup vs baseline: 1.4021x; 1.1048x over previous
//
#include <hip/hip_runtime.h>
#include <hip/hip_fp16.h>

// GCN encoder, N=50000, E=800000, 128 -> 96 (relu) -> sum-pooled 64+64.
// Sum-pooled layer 2: out = (sum_u c[u]*h[u]) @ W + N*b,
//   c[u] = dinv[u]*(dinv[u] + rsum[u]),  rsum[u] = sum_{e: src=u} dinv[dst_e].
// Layer 1 with g[u] = (xW1)[u]*dinv[u]  (fp8 e4m3, x16 scale):
//   h[d] = relu( (dinv[d]/16)*(sum_{e->d} g_s[src] + g_s[d]) + b1 )
// 8 kernels: count -> degdinv -> offs -> place -> gemm(+cfac) -> agg -> vred -> out.
// Round-15 change: k_gemm uses MFMA 16x16x32 f16 (fp32 VALU path had a 7.8us
// FMA floor; MFMA makes it memory-bound ~5us). Computes C^T (W-frag as A
// operand, x-frag as B) so each lane holds 4 consecutive out-cols -> pk_fp8.
// Lessons pinned (rounds 9-14):
//  * NO device-scope spin-wait scans (atomic storm, +20us).
//  * NO per-block __threadfence/atomic-publish fusions (+20us; agent fences
//    force per-XCD L2 writeback). Kernel-boundary sync is cheaper.
//  * col stays INT; count/place chunk-major (c=bid&31) 1024-thread blocks.
//  * NSLICE 8 vs 16: null. agg unroll-8/NT: null (TLP-saturated).

#define NCHUNK 32
#define LOG_NCHUNK 5
#define NSLICE 16
#define SLICE_MAX 3136   // LDS hist capacity; N <= 16*3136
#define SORT_T 1024      // threads for count/place

typedef float v2f __attribute__((ext_vector_type(2)));
typedef float f32x4 __attribute__((ext_vector_type(4)));
typedef _Float16 half8 __attribute__((ext_vector_type(8)));

__device__ inline unsigned f2h(float a, float b) {
    __half2 h = __floats2half2_rn(a, b);
    return *reinterpret_cast<unsigned*>(&h);
}

// pack 4 floats -> 4 x fp8 e4m3 in one uint
__device__ inline unsigned pk_fp8(float a, float b, float c, float d) {
    int p = __builtin_amdgcn_cvt_pk_fp8_f32(a, b, 0, false);
    p = __builtin_amdgcn_cvt_pk_fp8_f32(c, d, p, true);
    return (unsigned)p;
}

__device__ inline void add_fp8(float4& acc, unsigned u) {
    v2f f;
    f = __builtin_amdgcn_cvt_pk_f32_fp8(u, false); acc.x += f.x; acc.y += f.y;
    f = __builtin_amdgcn_cvt_pk_f32_fp8(u, true);  acc.z += f.x; acc.w += f.y;
}

// ---- K1: per-(chunk,slice) dst histogram via LDS -> ushort pcount ----
__launch_bounds__(SORT_T)
__global__ void k_count(const int* __restrict__ dst, unsigned short* __restrict__ pcount,
                        int N, int E, int chunkE, int sliceN) {
    int c = blockIdx.x & (NCHUNK - 1), s = blockIdx.x >> LOG_NCHUNK;
    int nbase = s * sliceN;
    __shared__ int hist[SLICE_MAX];
    for (int j = threadIdx.x; j < sliceN; j += SORT_T) hist[j] = 0;
    __syncthreads();
    int e0 = c * chunkE, e1 = min(e0 + chunkE, E);
    int ne = e1 - e0;
    const int4* d4 = (const int4*)(dst + e0);
    int n4 = ne >> 2;
    for (int i = threadIdx.x; i < n4; i += SORT_T) {
        int4 d = d4[i];
        unsigned q;
        q = (unsigned)(d.x - nbase); if (q < (unsigned)sliceN) atomicAdd(&hist[q], 1);
        q = (unsigned)(d.y - nbase); if (q < (unsigned)sliceN) atomicAdd(&hist[q], 1);
        q = (unsigned)(d.z - nbase); if (q < (unsigned)sliceN) atomicAdd(&hist[q], 1);
        q = (unsigned)(d.w - nbase); if (q < (unsigned)sliceN) atomicAdd(&hist[q], 1);
    }
    if (threadIdx.x < (ne & 3)) {
        int d = dst[e0 + (n4 << 2) + threadIdx.x];
        unsigned q = (unsigned)(d - nbase);
        if (q < (unsigned)sliceN) atomicAdd(&hist[q], 1);
    }
    __syncthreads();
    for (int j = threadIdx.x; j < sliceN; j += SORT_T) {
        int n = nbase + j;
        if (n < N) pcount[(size_t)c * N + n] = (unsigned short)hist[j];
    }
}

// ---- K2: deg = sum over chunks (ushort); dinv; per-block sum of deg ----
__launch_bounds__(256)
__global__ void k_degdinv(const unsigned short* __restrict__ pcount, int* __restrict__ deg,
                          float* __restrict__ dinv, int* __restrict__ blocksum, int N) {
    int tid = threadIdx.x;
    int n = blockIdx.x * 256 + tid;
    int s = 0;
    if (n < N) {
        #pragma unroll
        for (int c = 0; c < NCHUNK; ++c) s += pcount[(size_t)c * N + n];
        deg[n] = s;
        dinv[n] = rsqrtf((float)(s + 1));
    }
    __shared__ int sh[256];
    sh[tid] = s;
    __syncthreads();
    #pragma unroll
    for (int off = 128; off; off >>= 1) {
        if (tid < off) sh[tid] += sh[tid + off];
        __syncthreads();
    }
    if (tid == 0) blocksum[blockIdx.x] = sh[0];
}

// ---- K3: per-block scan of deg -> rowptr; pcount -> abs offsets (int) ----
__launch_bounds__(256)
__global__ void k_offs(const unsigned short* __restrict__ pcount, int* __restrict__ offs,
                       const int* __restrict__ deg, const int* __restrict__ blocksum,
                       int* __restrict__ rowptr, int N, int E, int nb) {
    int tid = threadIdx.x;
    __shared__ int sh[256];
    int bs = (tid < nb && tid < (int)blockIdx.x) ? blocksum[tid] : 0;
    sh[tid] = bs;
    __syncthreads();
    #pragma unroll
    for (int off = 128; off; off >>= 1) {
        if (tid < off) sh[tid] += sh[tid + off];
        __syncthreads();
    }
    int blockoff = sh[0];
    __syncthreads();
    int n = blockIdx.x * 256 + tid;
    int v = (n < N) ? deg[n] : 0;
    sh[tid] = v;
    __syncthreads();
    for (int off = 1; off < 256; off <<= 1) {
        int t = (tid >= off) ? sh[tid - off] : 0;
        __syncthreads();
        sh[tid] += t;
        __syncthreads();
    }
    int run = blockoff + sh[tid] - v;   // exclusive prefix
    if (n < N) {
        rowptr[n] = run;
        #pragma unroll
        for (int c = 0; c < NCHUNK; ++c) {
            size_t ix = (size_t)c * N + n;
            int t = pcount[ix];
            offs[ix] = run;
            run += t;
        }
    }
    if (blockIdx.x == 0 && tid == 0) rowptr[N] = E;
}

// ---- K4: place edges into col (int) via LDS cursors; rsum partials into offs ----
__launch_bounds__(SORT_T)
__global__ void k_place(const int* __restrict__ src, const int* __restrict__ dst,
                        const float* __restrict__ dinv, int* __restrict__ offs,
                        int* __restrict__ col, int N, int E, int chunkE, int sliceN) {
    int c = blockIdx.x & (NCHUNK - 1), s = blockIdx.x >> LOG_NCHUNK;
    int nbase = s * sliceN;
    __shared__ int cur[SLICE_MAX];
    __shared__ float rs[SLICE_MAX];
    for (int j = threadIdx.x; j < sliceN; j += SORT_T) {
        int n = nbase + j;
        cur[j] = (n < N) ? offs[(size_t)c * N + n] : 0;
        rs[j] = 0.f;
    }
    __syncthreads();
    int e0 = c * chunkE, e1 = min(e0 + chunkE, E);
    int ne = e1 - e0;
    const int4* s4 = (const int4*)(src + e0);
    const int4* d4 = (const int4*)(dst + e0);
    int n4 = ne >> 2;
    for (int i = threadIdx.x; i < n4; i += SORT_T) {
        int4 sv = s4[i];
        int4 dv = d4[i];
        unsigned qd, qs;
        qd = (unsigned)(dv.x - nbase);
        if (qd < (unsigned)sliceN) { int p = atomicAdd(&cur[qd], 1); col[p] = sv.x; }
        qs = (unsigned)(sv.x - nbase);
        if (qs < (unsigned)sliceN) atomicAdd(&rs[qs], dinv[dv.x]);
        qd = (unsigned)(dv.y - nbase);
        if (qd < (unsigned)sliceN) { int p = atomicAdd(&cur[qd], 1); col[p] = sv.y; }
        qs = (unsigned)(sv.y - nbase);
        if (qs < (unsigned)sliceN) atomicAdd(&rs[qs], dinv[dv.y]);
        qd = (unsigned)(dv.z - nbase);
        if (qd < (unsigned)sliceN) { int p = atomicAdd(&cur[qd], 1); col[p] = sv.z; }
        qs = (unsigned)(sv.z - nbase);
        if (qs < (unsigned)sliceN) atomicAdd(&rs[qs], dinv[dv.z]);
        qd = (unsigned)(dv.w - nbase);
        if (qd < (unsigned)sliceN) { int p = atomicAdd(&cur[qd], 1); col[p] = sv.w; }
        qs = (unsigned)(sv.w - nbase);
        if (qs < (unsigned)sliceN) atomicAdd(&rs[qs], dinv[dv.w]);
    }
    if (threadIdx.x < (ne & 3)) {
        int e = e0 + (n4 << 2) + threadIdx.x;
        int sv = src[e], dv = dst[e];
        unsigned qd = (unsigned)(dv - nbase);
        if (qd < (unsigned)sliceN) { int p = atomicAdd(&cur[qd], 1); col[p] = sv; }
        unsigned qs = (unsigned)(sv - nbase);
        if (qs < (unsigned)sliceN) atomicAdd(&rs[qs], dinv[dv]);
    }
    __syncthreads();
    float* prs = (float*)offs;   // offs[c][this slice] dead after load -> reuse
    for (int j = threadIdx.x; j < sliceN; j += SORT_T) {
        int n = nbase + j;
        if (n < N) prs[(size_t)c * N + n] = rs[j];
    }
}

// ---- K5: g = fp8(16*(x @ W1)*dinv[row]) via MFMA 16x16x32 f16; fused cfac ----
// Block: 256 thr = 4 waves, 64 rows (16/wave), all 96 cols. Computes C^T:
// A-operand = W1 fragment (out-col = M dim), B-operand = x fragment (row = N).
// D: lane&15 -> x-row, (lane>>4)*4+reg -> out-col => 4 consecutive cols/lane.
__launch_bounds__(256)
__global__ void k_gemm(const float* __restrict__ x, const float* __restrict__ W1,
                       const float* __restrict__ dinv, const float* __restrict__ prs,
                       float* __restrict__ cfac, unsigned* __restrict__ g, int n) {
    __shared__ float Ws[128 * 96];      // 48 KB, W1 staged linear
    __shared__ uint4 Whu4[24 * 64];     // 24 KB, fp16 A-frags: [ks*6+ct][lane]
    int tid = threadIdx.x;
    {   // stage W1 (12288 floats = 3072 float4)
        const float4* wsrc = (const float4*)W1;
        float4* wdst = (float4*)Ws;
        #pragma unroll
        for (int i = 0; i < 12; ++i) wdst[tid + 256 * i] = wsrc[tid + 256 * i];
    }
    // fused rsum->cfac for this block's 64 rows (overlaps staging)
    {
        int r = blockIdx.x * 64 + tid;
        if (tid < 64 && r < n) {
            float s = 0.f;
            #pragma unroll
            for (int c = 0; c < NCHUNK; ++c) s += prs[(size_t)c * n + r];
            float dv = dinv[r];
            cfac[r] = dv * (dv + s);
        }
    }
    __syncthreads();

    // build fp16 W fragments: frag (ks,ct), lane l holds W1[ks*32+(l>>4)*8+j][ct*16+(l&15)]
    for (int idx = tid; idx < 24 * 64; idx += 256) {
        int lane = idx & 63;
        int frag = idx >> 6;
        int ks = frag / 6, ct = frag - ks * 6;
        int k0 = ks * 32 + (lane >> 4) * 8;
        int c = ct * 16 + (lane & 15);
        const float* wsp = Ws + (size_t)k0 * 96 + c;
        Whu4[idx] = make_uint4(f2h(wsp[0],   wsp[96]),
                               f2h(wsp[192], wsp[288]),
                               f2h(wsp[384], wsp[480]),
                               f2h(wsp[576], wsp[672]));
    }
    __syncthreads();

    int wid = tid >> 6, lane = tid & 63;
    int xrow = blockIdx.x * 64 + wid * 16 + (lane & 15);
    bool vrow = xrow < n;
    const float4* xp = (const float4*)(x + (size_t)(vrow ? xrow : 0) * 128);

    f32x4 acc[6];
    #pragma unroll
    for (int ct = 0; ct < 6; ++ct) acc[ct] = (f32x4){0.f, 0.f, 0.f, 0.f};

    #pragma unroll
    for (int ks = 0; ks < 4; ++ks) {
        float4 xa = xp[ks * 8 + (lane >> 4) * 2];
        float4 xb = xp[ks * 8 + (lane >> 4) * 2 + 1];
        half8 bf;
        bf[0] = (_Float16)xa.x; bf[1] = (_Float16)xa.y;
        bf[2] = (_Float16)xa.z; bf[3] = (_Float16)xa.w;
        bf[4] = (_Float16)xb.x; bf[5] = (_Float16)xb.y;
        bf[6] = (_Float16)xb.z; bf[7] = (_Float16)xb.w;
        #pragma unroll
        for (int ct = 0; ct < 6; ++ct) {
            half8 af = *reinterpret_cast<const half8*>(&Whu4[(ks * 6 + ct) * 64 + lane]);
            acc[ct] = __builtin_amdgcn_mfma_f32_16x16x32_f16(af, bf, acc[ct], 0, 0, 0);
        }
    }

    if (vrow) {
        float dv = dinv[xrow] * 16.f;   // x16 scale for fp8 dynamic range
        unsigned* o = g + (size_t)xrow * 24 + (lane >> 4);
        #pragma unroll
        for (int ct = 0; ct < 6; ++ct) {
            o[ct * 4] = pk_fp8(acc[ct][0] * dv, acc[ct][1] * dv,
                               acc[ct][2] * dv, acc[ct][3] * dv);
        }
    }
}

// ---- K6: per-node fp8 gather (unroll-8, 4 accumulators, NT col loads) ----
#define AGG_NODES 16
#define AGG_T (AGG_NODES * 24)
__launch_bounds__(AGG_T)
__global__ void k_agg(const unsigned* __restrict__ g1, const int* __restrict__ col,
                      const int* __restrict__ rowptr, const float* __restrict__ dinv,
                      const float* __restrict__ cfac, const float* __restrict__ b1,
                      float* __restrict__ v_part, int n) {
    int tid = threadIdx.x;
    int nl = tid / 24;
    int ch = tid % 24;        // uint chunk of the 24-uint row (4 fp8 each)
    int d = blockIdx.x * AGG_NODES + nl;

    __shared__ float4 sh[AGG_NODES][24];

    float4 contrib = make_float4(0.f, 0.f, 0.f, 0.f);
    if (d < n) {
        float dds = dinv[d] * 0.0625f;   // undo x16 storage scale
        int e0 = rowptr[d], e1 = rowptr[d + 1];
        float4 aA = make_float4(0.f, 0.f, 0.f, 0.f);
        float4 aB = make_float4(0.f, 0.f, 0.f, 0.f);
        float4 aC = make_float4(0.f, 0.f, 0.f, 0.f);
        float4 aD = make_float4(0.f, 0.f, 0.f, 0.f);
        int e = e0;
        for (; e + 8 <= e1; e += 8) {
            int s0 = __builtin_nontemporal_load(col + e);
            int s1 = __builtin_nontemporal_load(col + e + 1);
            int s2 = __builtin_nontemporal_load(col + e + 2);
            int s3 = __builtin_nontemporal_load(col + e + 3);
            int s4 = __builtin_nontemporal_load(col + e + 4);
            int s5 = __builtin_nontemporal_load(col + e + 5);
            int s6 = __builtin_nontemporal_load(col + e + 6);
            int s7 = __builtin_nontemporal_load(col + e + 7);
            unsigned u0 = g1[(size_t)s0 * 24 + ch];
            unsigned u1 = g1[(size_t)s1 * 24 + ch];
            unsigned u2 = g1[(size_t)s2 * 24 + ch];
            unsigned u3 = g1[(size_t)s3 * 24 + ch];
            unsigned u4 = g1[(size_t)s4 * 24 + ch];
            unsigned u5 = g1[(size_t)s5 * 24 + ch];
            unsigned u6 = g1[(size_t)s6 * 24 + ch];
            unsigned u7 = g1[(size_t)s7 * 24 + ch];
            add_fp8(aA, u0); add_fp8(aB, u1); add_fp8(aC, u2); add_fp8(aD, u3);
            add_fp8(aA, u4); add_fp8(aB, u5); add_fp8(aC, u6); add_fp8(aD, u7);
        }
        for (; e + 2 <= e1; e += 2) {
            int s0 = __builtin_nontemporal_load(col + e);
            int s1 = __builtin_nontemporal_load(col + e + 1);
            unsigned u0 = g1[(size_t)s0 * 24 + ch];
            unsigned u1 = g1[(size_t)s1 * 24 + ch];
            add_fp8(aA, u0); add_fp8(aB, u1);
        }
        if (e < e1) {
            int s0 = __builtin_nontemporal_load(col + e);
            add_fp8(aC, g1[(size_t)s0 * 24 + ch]);
        }
        add_fp8(aD, g1[(size_t)d * 24 + ch]);   // analytic self-loop
        float4 b1c = ((const float4*)b1)[ch];
        float cd = cfac[d];
        float hx = fmaxf(fmaf(dds, (aA.x + aB.x) + (aC.x + aD.x), b1c.x), 0.f);
        float hy = fmaxf(fmaf(dds, (aA.y + aB.y) + (aC.y + aD.y), b1c.y), 0.f);
        float hz = fmaxf(fmaf(dds, (aA.z + aB.z) + (aC.z + aD.z), b1c.z), 0.f);
        float hw = fmaxf(fmaf(dds, (aA.w + aB.w) + (aC.w + aD.w), b1c.w), 0.f);
        contrib = make_float4(cd * hx, cd * hy, cd * hz, cd * hw);
    }
    sh[nl][ch] = contrib;
    __syncthreads();
    #pragma unroll
    for (int off = 8; off >= 1; off >>= 1) {
        if (nl < off) {
            float4 a = sh[nl][ch];
            float4 b = sh[nl + off][ch];
            a.x += b.x; a.y += b.y; a.z += b.z; a.w += b.w;
            sh[nl][ch] = a;
        }
        __syncthreads();
    }
    if (tid < 24) {
        ((float4*)(v_part + (size_t)blockIdx.x * 96))[tid] = sh[0][tid];
    }
}

// ---- K7: reduce v_part -> v[96] (fence-free) ----
__global__ void k_vred(const float* __restrict__ vp, float* __restrict__ v, int nb) {
    int j = blockIdx.x;
    float s = 0.f;
    for (int i = threadIdx.x; i < nb; i += 256) s += vp[(size_t)i * 96 + j];
    __shared__ float sh[256];
    sh[threadIdx.x] = s;
    __syncthreads();
    for (int off = 128; off; off >>= 1) {
        if (threadIdx.x < off) sh[threadIdx.x] += sh[threadIdx.x + off];
        __syncthreads();
    }
    if (threadIdx.x == 0) v[j] = sh[0];
}

// ---- K8: mu = v@W_mu + N*b_mu ; logvar = v@W_lv + N*b_lv ----
__global__ void k_out(const float* __restrict__ v,
                      const float* __restrict__ Wmu, const float* __restrict__ bmu,
                      const float* __restrict__ Wlv, const float* __restrict__ blv,
                      float* __restrict__ out, float nN) {
    int tid = threadIdx.x;
    const float* W = (tid < 64) ? Wmu : Wlv;
    const float* b = (tid < 64) ? bmu : blv;
    int j = tid & 63;
    float s = 0.f;
    #pragma unroll
    for (int k = 0; k < 96; ++k) s = fmaf(v[k], W[k * 64 + j], s);
    out[tid] = s + nN * b[j];
}

extern "C" void kernel_launch(void* const* d_in, const int* in_sizes, int n_in,
                              void* d_out, int out_size, void* d_ws, size_t ws_size,
                              hipStream_t stream) {
    const float* x   = (const float*)d_in[0];
    const int*   ei  = (const int*)d_in[1];
    const float* W1  = (const float*)d_in[2];
    const float* b1  = (const float*)d_in[3];
    const float* Wmu = (const float*)d_in[4];
    const float* bmu = (const float*)d_in[5];
    const float* Wlv = (const float*)d_in[6];
    const float* blv = (const float*)d_in[7];
    float* out = (float*)d_out;

    const int N = in_sizes[0] / 128;   // 50000
    const int E = in_sizes[1] / 2;     // 800000
    const int* src = ei;
    const int* dst = ei + E;

    const int chunkE = (((E + NCHUNK - 1) / NCHUNK) + 3) & ~3;   // 25000
    const int sliceN = (N + NSLICE - 1) / NSLICE;                // 3125
    const int gN = (N + 255) / 256;                              // 196

    size_t off = 0;
    auto alloc = [&](size_t bytes) -> char* {
        off = (off + 255) & ~(size_t)255;
        char* p = (char*)d_ws + off;
        off += bytes;
        return p;
    };
    unsigned short* pcount = (unsigned short*)alloc((size_t)NCHUNK * N * 2);  // counts
    int*      offsb    = (int*)alloc((size_t)NCHUNK * N * 4);  // offsets -> rsum partials
    int*      rowptr   = (int*)alloc((size_t)(N + 1) * 4);
    int*      col      = (int*)alloc((size_t)E * 4);
    int*      deg      = (int*)alloc((size_t)N * 4);
    float*    dinv     = (float*)alloc((size_t)N * 4);
    float*    cfac     = (float*)alloc((size_t)N * 4);
    int*      blocksum = (int*)alloc((size_t)gN * 4);
    unsigned* g        = (unsigned*)alloc((size_t)N * 96);     // fp8 e4m3, 24 uints/row
    const int nAggBlocks = (N + AGG_NODES - 1) / AGG_NODES;    // 3125
    float*    v_part   = (float*)alloc((size_t)nAggBlocks * 96 * 4);
    float*    v        = (float*)alloc(96 * 4);

    k_count<<<NCHUNK * NSLICE, SORT_T, 0, stream>>>(dst, pcount, N, E, chunkE, sliceN);
    k_degdinv<<<gN, 256, 0, stream>>>(pcount, deg, dinv, blocksum, N);
    k_offs<<<gN, 256, 0, stream>>>(pcount, offsb, deg, blocksum, rowptr, N, E, gN);
    k_place<<<NCHUNK * NSLICE, SORT_T, 0, stream>>>(src, dst, dinv, offsb, col, N, E, chunkE, sliceN);
    k_gemm<<<(N + 63) / 64, 256, 0, stream>>>(x, W1, dinv, (const float*)offsb, cfac, g, N);
    k_agg<<<nAggBlocks, AGG_T, 0, stream>>>(g, col, rowptr, dinv, cfac, b1, v_part, N);
    k_vred<<<96, 256, 0, stream>>>(v_part, v, nAggBlocks);
    k_out<<<1, 128, 0, stream>>>(v, Wmu, bmu, Wlv, blv, out, (float)N);
}